// Round 2
// baseline (2270.873 us; speedup 1.0000x reference)
//
#include <hip/hip_runtime.h>
#include <hip/hip_bf16.h>
#include <hip/hip_fp16.h>

#define BT 16384
#define F 32
#define H 256
#define FH 8192
#define SPLITK 4

typedef _Float16 half8 __attribute__((ext_vector_type(8)));
typedef float float4v __attribute__((ext_vector_type(4)));

#define GLD_LDS(gsrc, ldst) \
    __builtin_amdgcn_global_load_lds( \
        (const __attribute__((address_space(1))) void*)(gsrc), \
        (__attribute__((address_space(3))) void*)(ldst), 16, 0, 0)

// ---------------------------------------------------------------------------
// Prep: transpose w2/wg/wf (F,H_contr,H_out) fp32 -> [f][n_out][h_contr] fp16
// ---------------------------------------------------------------------------
__global__ __launch_bounds__(256) void transpose_w_kernel(
    const float* __restrict__ w2, const float* __restrict__ wg,
    const float* __restrict__ wf, _Float16* __restrict__ wt)
{
    __shared__ float tile[64][65];
    int bid = blockIdx.x;
    int tens = bid >> 9, rem = bid & 511;
    int f = rem >> 4, tl = rem & 15;
    int hb = (tl >> 2) * 64, nb = (tl & 3) * 64;
    const float* src = (tens == 0 ? w2 : (tens == 1 ? wg : wf)) + f * 65536;
    _Float16* dst = wt + (size_t)tens * 2097152 + f * 65536;
    int lane = threadIdx.x & 63, w = threadIdx.x >> 6;
    for (int i = 0; i < 16; ++i) {
        int r = i * 4 + w;
        tile[r][lane] = src[(hb + r) * 256 + nb + lane];
    }
    __syncthreads();
    for (int i = 0; i < 16; ++i) {
        int c = i * 4 + w;
        dst[(nb + c) * 256 + hb + lane] = (_Float16)tile[lane][c];
    }
}

// ---------------------------------------------------------------------------
// Prep: Wcat[n][k] fp16, n<256 from sw1 (8192,256), n in [256,288) from ssw
// ---------------------------------------------------------------------------
__global__ __launch_bounds__(256) void transpose_s_kernel(
    const float* __restrict__ sw1, const float* __restrict__ ssw,
    _Float16* __restrict__ wcat)
{
    __shared__ float tile[64][65];
    int bid = blockIdx.x;
    int lane = threadIdx.x & 63, w = threadIdx.x >> 6;
    if (bid < 512) {
        int k0 = (bid >> 2) * 64, n0 = (bid & 3) * 64;
        for (int i = 0; i < 16; ++i) {
            int r = i * 4 + w;
            tile[r][lane] = sw1[(size_t)(k0 + r) * 256 + n0 + lane];
        }
        __syncthreads();
        for (int i = 0; i < 16; ++i) {
            int c = i * 4 + w;
            wcat[(size_t)(n0 + c) * FH + k0 + lane] = (_Float16)tile[lane][c];
        }
    } else {
        int k0 = (bid - 512) * 64;
        int t = threadIdx.x;
        for (int i = 0; i < 8; ++i) {
            int idx = t + i * 256;
            int r = idx >> 5, cc = idx & 31;
            tile[r][cc] = ssw[(size_t)(k0 + r) * 32 + cc];
        }
        __syncthreads();
        for (int i = 0; i < 8; ++i) {
            int idx = t + i * 256;
            int c = idx >> 6, rr = idx & 63;
            wcat[(size_t)(256 + c) * FH + k0 + rr] = (_Float16)tile[rr][c];
        }
    }
}

// ---------------------------------------------------------------------------
// grn gemm stage with global_load_lds + XOR swizzle.
// Bs layout: 256 rows x 64 fp16 (unpadded). Row n, LDS chunk-pos cp (16B units)
// holds source chunk c = cp ^ (n&7). Fragment read for k-chunk (4*ks+q) of row
// n reads cp = (4*ks+q) ^ (n&7).
// ---------------------------------------------------------------------------
__device__ __forceinline__ void gemm_stage(
    const _Float16* __restrict__ Bsrc,   // weight slice for this f: [n][k], k contig
    const _Float16* As, _Float16* Bs,
    int t, int wv, int ln, int q, float4v acc[2][4])
{
    for (int kc = 0; kc < 4; ++kc) {
        __syncthreads();
#pragma unroll
        for (int it = 0; it < 8; ++it) {
            int s = it * 256 + t;          // LDS slot (wave-contiguous)
            int n = s >> 3;
            int c = (s & 7) ^ (n & 7);     // source chunk (xor swizzle)
            GLD_LDS(Bsrc + n * 256 + kc * 64 + c * 8, Bs + s * 8);
        }
        __syncthreads();
        for (int ks = 0; ks < 2; ++ks) {
            int kb = kc * 64 + ks * 32 + q * 8;
            half8 a0 = *(const half8*)&As[(0 + ln) * 264 + kb];
            half8 a1 = *(const half8*)&As[(16 + ln) * 264 + kb];
#pragma unroll
            for (int nt = 0; nt < 4; ++nt) {
                int n = wv * 64 + nt * 16 + ln;
                int cp = (ks * 4 + q) ^ (n & 7);
                half8 b8 = *(const half8*)&Bs[n * 64 + cp * 8];
                acc[0][nt] = __builtin_amdgcn_mfma_f32_16x16x32_f16(a0, b8, acc[0][nt], 0, 0, 0);
                acc[1][nt] = __builtin_amdgcn_mfma_f32_16x16x32_f16(a1, b8, acc[1][nt], 0, 0, 0);
            }
        }
    }
}

// ---------------------------------------------------------------------------
// Fused per-feature GRN: 3 GEMMs (K=256) + GLU + residual + LayerNorm
// One block = 32 tokens x one feature f. stacked written fp16 (chunk-local).
// ---------------------------------------------------------------------------
__global__ __launch_bounds__(256) void grn_kernel(
    const float* __restrict__ x, const float* __restrict__ w1, const float* __restrict__ b1,
    const float* __restrict__ b2, const float* __restrict__ bg, const float* __restrict__ bfv_,
    const float* __restrict__ gamma, const float* __restrict__ beta,
    const float* __restrict__ wsk, const float* __restrict__ bsk,
    const _Float16* __restrict__ w2t, const _Float16* __restrict__ wgt,
    const _Float16* __restrict__ wft, _Float16* __restrict__ stacked, int tok_base)
{
    __shared__ __align__(16) char smem[53248];
    _Float16* As = (_Float16*)smem;                     // 32 x 264 fp16
    float* xs = (float*)(smem + 16896);                 // 32
    _Float16* Bs = (_Float16*)(smem + 17024);           // 256 x 64 fp16 (swizzled)
    float* ys = (float*)(smem + 17024);                 // 32 x 265 f32 (alias Bs)
    float* red = (float*)(smem + 17024 + 33920);        // 512
    float* mv = (float*)(smem + 17024 + 33920 + 2048);  // 64

    const int f = blockIdx.y;
    const int tok0 = blockIdx.x * 32;                   // chunk-local
    const int t = threadIdx.x;
    const int wv = t >> 6;
    const int ln = t & 15;
    const int q = (t & 63) >> 4;

    if (t < 32) xs[t] = x[(size_t)(tok_base + tok0 + t) * F + f];
    __syncthreads();

    // A = elu(x * w1 + b1), fp16 into LDS (32 x 256, stride 264)
    {
        float w1v = w1[f * H + t];
        float b1v = b1[f * H + t];
#pragma unroll 4
        for (int i = 0; i < 32; ++i) {
            float z = xs[i] * w1v + b1v;
            float e = z > 0.f ? z : (expf(z) - 1.f);
            As[i * 264 + t] = (_Float16)e;
        }
    }
    // stage 1: h2 = A @ w2 + b2
    float4v acc1[2][4];
#pragma unroll
    for (int mt = 0; mt < 2; ++mt)
#pragma unroll
        for (int nt = 0; nt < 4; ++nt)
#pragma unroll
            for (int r = 0; r < 4; ++r) acc1[mt][nt][r] = 0.f;
    gemm_stage(w2t + (size_t)f * 65536, As, Bs, t, wv, ln, q, acc1);

    __syncthreads();  // all stage-1 MFMA reads of As done
    {
        const float* b2f = b2 + f * H;
#pragma unroll
        for (int mt = 0; mt < 2; ++mt)
#pragma unroll
            for (int nt = 0; nt < 4; ++nt) {
                int n = wv * 64 + nt * 16 + ln;
                float b2v = b2f[n];
#pragma unroll
                for (int r = 0; r < 4; ++r) {
                    int m = mt * 16 + q * 4 + r;
                    As[m * 264 + n] = (_Float16)(acc1[mt][nt][r] + b2v);
                }
            }
    }
    // stage 2: Cg = h2 @ wg, Cf = h2 @ wf (sequential, reuse Bs)
    float4v accG[2][4], accF[2][4];
#pragma unroll
    for (int mt = 0; mt < 2; ++mt)
#pragma unroll
        for (int nt = 0; nt < 4; ++nt)
#pragma unroll
            for (int r = 0; r < 4; ++r) { accG[mt][nt][r] = 0.f; accF[mt][nt][r] = 0.f; }
    gemm_stage(wgt + (size_t)f * 65536, As, Bs, t, wv, ln, q, accG);
    gemm_stage(wft + (size_t)f * 65536, As, Bs, t, wv, ln, q, accF);

    // epilogue: y = sigmoid(Cg+bg)*(Cf+bf) + x*ws + bs, into LDS f32
    __syncthreads();
    {
        const float* bgf = bg + f * H;
        const float* bff = bfv_ + f * H;
        const float* wsf = wsk + f * H;
        const float* bsf = bsk + f * H;
#pragma unroll
        for (int mt = 0; mt < 2; ++mt)
#pragma unroll
            for (int nt = 0; nt < 4; ++nt) {
                int n = wv * 64 + nt * 16 + ln;
                float bgv = bgf[n], bfv = bff[n], wsv = wsf[n], bsv = bsf[n];
#pragma unroll
                for (int r = 0; r < 4; ++r) {
                    int m = mt * 16 + q * 4 + r;
                    float cg = accG[mt][nt][r] + bgv;
                    float cf = accF[mt][nt][r] + bfv;
                    float sig = 1.f / (1.f + expf(-cg));
                    ys[m * 265 + n] = sig * cf + xs[m] * wsv + bsv;
                }
            }
    }
    __syncthreads();
    // LayerNorm over H=256 per row. Read pattern j*8+seg: 8 lanes of a row hit
    // 8 consecutive banks (was seg*32+j: 8-way same-bank conflict).
    {
        int row = t >> 3, seg = t & 7;
        float s1 = 0.f, s2 = 0.f;
#pragma unroll 8
        for (int j = 0; j < 32; ++j) {
            float v = ys[row * 265 + j * 8 + seg];
            s1 += v; s2 += v * v;
        }
        red[t] = s1; red[256 + t] = s2;
    }
    __syncthreads();
    if (t < 32) {
        float a = 0.f, b = 0.f;
        for (int s = 0; s < 8; ++s) { a += red[t * 8 + s]; b += red[256 + t * 8 + s]; }
        float mean = a * (1.f / 256.f);
        float var = b * (1.f / 256.f) - mean * mean;
        mv[t] = mean;
        mv[32 + t] = rsqrtf(var + 1e-5f);
    }
    __syncthreads();
    {
        float gv = gamma[f * H + t], bv = beta[f * H + t];
        for (int i = 0; i < 32; ++i) {
            float v = (ys[i * 265 + t] - mv[i]) * mv[32 + i] * gv + bv;
            stacked[(size_t)(tok0 + i) * FH + f * H + t] = (_Float16)v;
        }
    }
}

// ---------------------------------------------------------------------------
// Selection GEMM v2: BM=128, BK=32, 512 threads (8 waves = 2m x 4n),
// double-buffered LDS with issue-next-stage-before-compute prefetch.
// Grid (C/128, SPLITK). Each block: 128 tokens x N=288 x K=2048 -> plain
// stores into sh_part[kb]/sres_part[kb] (biases folded into tail).
// LDS rows are 32 fp16 (64B); XOR swizzle: chunk cp holds source chunk
// cp ^ ((row>>1)&3)  (bijective involution; verified <=2-way bank aliasing
// on both ds_read_b128 and staging).
// ---------------------------------------------------------------------------
__global__ __launch_bounds__(512, 4) void sel_gemm_kernel(
    const _Float16* __restrict__ stacked, const _Float16* __restrict__ wcat,
    float* __restrict__ sh_part, float* __restrict__ sres_part, int C)
{
    __shared__ __align__(16) _Float16 As2[2][128 * 32];   // 2 x 8 KB
    __shared__ __align__(16) _Float16 Bs2[2][288 * 32];   // 2 x 18 KB
    const int t = threadIdx.x;
    const int wv = t >> 6;
    const int ln = t & 15, q = (t & 63) >> 4;
    const int wm = wv >> 2, wn = wv & 3;                 // 2 m-rows x 4 n-cols
    const int tok0 = blockIdx.x * 128;                   // chunk-local
    const int kb = blockIdx.y;                           // k-slice 0..3
    const int NT = (wn < 2) ? 5 : 4;                     // n-tiles per wave (18 total)

    // staging geometry: slot s -> row (s>>2), chunk-pos (s&3),
    // source chunk c = (s&3) ^ (((s>>2)>>1)&3) = (t&3)^((t>>3)&3) for s=t+512i
    const int nS = t >> 2;
    const int cOff = ((t & 3) ^ ((t >> 3) & 3)) * 8;     // fp16 elements

    float4v acc[4][5];
#pragma unroll
    for (int mt = 0; mt < 4; ++mt)
#pragma unroll
        for (int i = 0; i < 5; ++i)
#pragma unroll
            for (int r = 0; r < 4; ++r) acc[mt][i][r] = 0.f;

#define SEL_STAGE(buf, kcc)                                                        \
    {                                                                              \
        const int k0_ = (kb * 64 + (kcc)) * 32;                                    \
        GLD_LDS(stacked + (size_t)(tok0 + nS) * FH + k0_ + cOff,                   \
                &As2[buf][t * 8]);                                                 \
        GLD_LDS(wcat + (size_t)nS * FH + k0_ + cOff, &Bs2[buf][t * 8]);            \
        GLD_LDS(wcat + (size_t)(128 + nS) * FH + k0_ + cOff,                       \
                &Bs2[buf][(512 + t) * 8]);                                         \
        if (t < 128)                                                               \
            GLD_LDS(wcat + (size_t)(256 + nS) * FH + k0_ + cOff,                   \
                    &Bs2[buf][(1024 + t) * 8]);                                    \
    }

    SEL_STAGE(0, 0);
    __syncthreads();                                     // drain prologue stage

    for (int kc = 0; kc < 64; ++kc) {
        const int cur = kc & 1;
        if (kc < 63) SEL_STAGE(cur ^ 1, kc + 1);         // prefetch next K-step
        const _Float16* As = As2[cur];
        const _Float16* Bs = Bs2[cur];
        half8 af[4];
#pragma unroll
        for (int mt = 0; mt < 4; ++mt) {
            int row = wm * 64 + mt * 16 + ln;
            int cp = q ^ ((row >> 1) & 3);
            af[mt] = *(const half8*)&As[row * 32 + cp * 8];
        }
        for (int i = 0; i < NT; ++i) {
            int row = (wn + 4 * i) * 16 + ln;
            int cp = q ^ ((row >> 1) & 3);
            half8 b8 = *(const half8*)&Bs[row * 32 + cp * 8];
#pragma unroll
            for (int mt = 0; mt < 4; ++mt)
                acc[mt][i] = __builtin_amdgcn_mfma_f32_16x16x32_f16(af[mt], b8, acc[mt][i], 0, 0, 0);
        }
        __syncthreads();  // compiler drains vmcnt before barrier: next stage done,
                          // and all waves finished reading buf[cur]
    }
#undef SEL_STAGE

    float* shp = sh_part + (size_t)kb * ((size_t)C * 256);
    float* srp = sres_part + (size_t)kb * ((size_t)C * 32);
    for (int i = 0; i < NT; ++i) {
        int n = (wn + 4 * i) * 16 + ln;
#pragma unroll
        for (int mt = 0; mt < 4; ++mt)
#pragma unroll
            for (int r = 0; r < 4; ++r) {
                int m = tok0 + wm * 64 + mt * 16 + q * 4 + r;
                float v = acc[mt][i][r];
                if (n < 256) shp[(size_t)m * 256 + n] = v;
                else         srp[(size_t)m * 32 + (n - 256)] = v;
            }
    }
}

// ---------------------------------------------------------------------------
// Fused selection tail + weighted sum. Block = 8 tokens (32 lanes each).
// Reduces the 4 split-K partials (+bias) -> elu -> fc2(256->32) -> GLU -> LN
// -> softmax -> out = sum_f stacked*w
// ---------------------------------------------------------------------------
__global__ __launch_bounds__(256) void tail_kernel(
    const float* __restrict__ sh_part, const float* __restrict__ sres_part,
    const _Float16* __restrict__ stacked,
    const float* __restrict__ sb1, const float* __restrict__ ssb,
    const float* __restrict__ sw2, const float* __restrict__ sb2,
    const float* __restrict__ swg, const float* __restrict__ sbg,
    const float* __restrict__ swf, const float* __restrict__ sbf,
    const float* __restrict__ sgam, const float* __restrict__ sbet,
    float* __restrict__ out, int tok_base, int C)
{
    __shared__ float sw2s[256 * 32];                    // 32 KB
    __shared__ float swgs[1024], swfs[1024];            // 8 KB
    __shared__ float shv[8][257];                       // 8 tokens x 256 (+pad)
    __shared__ float wls[8][33];
    const int t = threadIdx.x;
    const size_t shS = (size_t)C * 256;
    const size_t srS = (size_t)C * 32;
    for (int i = 0; i < 32; ++i) sw2s[t + i * 256] = sw2[t + i * 256];
    for (int i = 0; i < 4; ++i) {
        swgs[t + i * 256] = swg[t + i * 256];
        swfs[t + i * 256] = swf[t + i * 256];
    }
    // reduce split-K partials + bias, elu, stage for 8 tokens
    for (int i = 0; i < 8; ++i) {
        int idx = t + i * 256;
        int gg = idx >> 8, col = idx & 255;
        size_t o = (size_t)(blockIdx.x * 8 + gg) * 256 + col;
        float z = sb1[col] + sh_part[o] + sh_part[shS + o]
                + sh_part[2 * shS + o] + sh_part[3 * shS + o];
        shv[gg][col] = z > 0.f ? z : (expf(z) - 1.f);
    }
    __syncthreads();
    const int g = t >> 5;                               // token group 0..7
    const int j = t & 31;                               // feature index
    const int token = blockIdx.x * 8 + g;               // chunk-local
    // fc2: 256 -> 32
    float p = sb2[j];
    for (int k = 0; k < 256; ++k) p += shv[g][k] * sw2s[k * 32 + j];
    // GLU via width-32 shuffles
    float gacc = sbg[j], uacc = sbf[j];
#pragma unroll 8
    for (int i = 0; i < 32; ++i) {
        float tv = __shfl(p, i, 32);
        gacc += tv * swgs[i * 32 + j];
        uacc += tv * swfs[i * 32 + j];
    }
    float sig = 1.f / (1.f + expf(-gacc));
    size_t o2 = (size_t)token * 32 + j;
    float sresv = ssb[j] + sres_part[o2] + sres_part[srS + o2]
                + sres_part[2 * srS + o2] + sres_part[3 * srS + o2];
    float sv = sresv + sig * uacc;
    // LayerNorm over 32 lanes
    float s1 = sv, s2 = sv * sv;
    for (int off = 16; off; off >>= 1) {
        s1 += __shfl_xor(s1, off, 32);
        s2 += __shfl_xor(s2, off, 32);
    }
    float mean = s1 * (1.f / 32.f);
    float var = s2 * (1.f / 32.f) - mean * mean;
    float v = (sv - mean) * rsqrtf(var + 1e-5f) * sgam[j] + sbet[j];
    // softmax over 32 lanes
    float mx = v;
    for (int off = 16; off; off >>= 1) mx = fmaxf(mx, __shfl_xor(mx, off, 32));
    float e = expf(v - mx);
    float ssum = e;
    for (int off = 16; off; off >>= 1) ssum += __shfl_xor(ssum, off, 32);
    wls[g][j] = e / ssum;
    __syncthreads();
    // weighted sum over features for the block's 8 tokens
    for (int tk = 0; tk < 8; ++tk) {
        const _Float16* sp = stacked + (size_t)(blockIdx.x * 8 + tk) * FH;
        float a = 0.f;
#pragma unroll
        for (int f = 0; f < 32; ++f) a += (float)sp[f * 256 + t] * wls[tk][f];
        out[(size_t)(tok_base + blockIdx.x * 8 + tk) * 256 + t] = a;
    }
}

// ---------------------------------------------------------------------------
extern "C" void kernel_launch(void* const* d_in, const int* in_sizes, int n_in,
                              void* d_out, int out_size, void* d_ws, size_t ws_size,
                              hipStream_t stream)
{
    (void)in_sizes; (void)n_in; (void)out_size;
    const float* x    = (const float*)d_in[0];
    const float* w1   = (const float*)d_in[1];
    const float* b1   = (const float*)d_in[2];
    const float* w2   = (const float*)d_in[3];
    const float* b2   = (const float*)d_in[4];
    const float* wg   = (const float*)d_in[5];
    const float* bg   = (const float*)d_in[6];
    const float* wf   = (const float*)d_in[7];
    const float* bfp  = (const float*)d_in[8];
    const float* gamma= (const float*)d_in[9];
    const float* beta = (const float*)d_in[10];
    const float* wsk  = (const float*)d_in[11];
    const float* bsk  = (const float*)d_in[12];
    const float* sw1  = (const float*)d_in[13];
    const float* sb1  = (const float*)d_in[14];
    const float* sw2  = (const float*)d_in[15];
    const float* sb2  = (const float*)d_in[16];
    const float* swg  = (const float*)d_in[17];
    const float* sbg  = (const float*)d_in[18];
    const float* swf  = (const float*)d_in[19];
    const float* sbf  = (const float*)d_in[20];
    const float* sgam = (const float*)d_in[21];
    const float* sbet = (const float*)d_in[22];
    const float* ssw  = (const float*)d_in[23];
    const float* ssb  = (const float*)d_in[24];

    // ---- workspace layout, chunk size adaptive to ws_size ----
    // per-token: stacked 16384B + sh_part 4*1024B + sres_part 4*128B = 20992B
    const size_t fixedB = 12582912 + 4718592;            // wt (12 MiB) + wcat (4.5 MiB)
    int C = BT;                                          // tokens per chunk
    while (C > 512) {
        size_t need = fixedB + (size_t)C * 20992;
        if (need <= ws_size) break;
        C >>= 1;
    }
    const int nChunks = BT / C;

    char* ws = (char*)d_ws;
    _Float16* wt      = (_Float16*)ws;                                   // 3 x 2M fp16
    _Float16* wcat    = (_Float16*)(ws + 12582912);                      // 288 x 8192 fp16
    char* p = ws + fixedB;
    _Float16* stacked = (_Float16*)p;            p += (size_t)C * FH * 2;
    float* sh_part    = (float*)p;               p += (size_t)C * 256 * 4 * SPLITK;
    float* sres_part  = (float*)p;
    float* out        = (float*)d_out;

    hipLaunchKernelGGL(transpose_w_kernel, dim3(1536), dim3(256), 0, stream, w2, wg, wf, wt);
    hipLaunchKernelGGL(transpose_s_kernel, dim3(640), dim3(256), 0, stream, sw1, ssw, wcat);
    for (int c = 0; c < nChunks; ++c) {
        int tb = c * C;
        hipLaunchKernelGGL(grn_kernel, dim3(C / 32, 32), dim3(256), 0, stream,
                           x, w1, b1, b2, bg, bfp, gamma, beta, wsk, bsk,
                           wt, wt + 2097152, wt + 2 * 2097152, stacked, tb);
        hipLaunchKernelGGL(sel_gemm_kernel, dim3(C / 128, SPLITK), dim3(512), 0, stream,
                           stacked, wcat, sh_part, sres_part, C);
        hipLaunchKernelGGL(tail_kernel, dim3(C / 8), dim3(256), 0, stream,
                           sh_part, sres_part, stacked, sb1, ssb, sw2, sb2, swg, sbg, swf, sbf,
                           sgam, sbet, out, tb, C);
    }
}

// Round 3
// 1025.248 us; speedup vs baseline: 2.2149x; 2.2149x over previous
//
#include <hip/hip_runtime.h>
#include <hip/hip_bf16.h>
#include <hip/hip_fp16.h>

#define BT 16384
#define F 32
#define H 256
#define FH 8192
#define SPLITK 4

typedef _Float16 half8 __attribute__((ext_vector_type(8)));
typedef float float4v __attribute__((ext_vector_type(4)));

#define GLD_LDS(gsrc, ldst) \
    __builtin_amdgcn_global_load_lds( \
        (const __attribute__((address_space(1))) void*)(gsrc), \
        (__attribute__((address_space(3))) void*)(ldst), 16, 0, 0)

// ---------------------------------------------------------------------------
// Prep: transpose w2/wg/wf (F,H_contr,H_out) fp32 -> [f][n_out][h_contr] fp16
// ---------------------------------------------------------------------------
__global__ __launch_bounds__(256) void transpose_w_kernel(
    const float* __restrict__ w2, const float* __restrict__ wg,
    const float* __restrict__ wf, _Float16* __restrict__ wt)
{
    __shared__ float tile[64][65];
    int bid = blockIdx.x;
    int tens = bid >> 9, rem = bid & 511;
    int f = rem >> 4, tl = rem & 15;
    int hb = (tl >> 2) * 64, nb = (tl & 3) * 64;
    const float* src = (tens == 0 ? w2 : (tens == 1 ? wg : wf)) + f * 65536;
    _Float16* dst = wt + (size_t)tens * 2097152 + f * 65536;
    int lane = threadIdx.x & 63, w = threadIdx.x >> 6;
    for (int i = 0; i < 16; ++i) {
        int r = i * 4 + w;
        tile[r][lane] = src[(hb + r) * 256 + nb + lane];
    }
    __syncthreads();
    for (int i = 0; i < 16; ++i) {
        int c = i * 4 + w;
        dst[(nb + c) * 256 + hb + lane] = (_Float16)tile[lane][c];
    }
}

// ---------------------------------------------------------------------------
// Prep: Wcat[n][k] fp16, n<256 from sw1 (8192,256), n in [256,288) from ssw
// ---------------------------------------------------------------------------
__global__ __launch_bounds__(256) void transpose_s_kernel(
    const float* __restrict__ sw1, const float* __restrict__ ssw,
    _Float16* __restrict__ wcat)
{
    __shared__ float tile[64][65];
    int bid = blockIdx.x;
    int lane = threadIdx.x & 63, w = threadIdx.x >> 6;
    if (bid < 512) {
        int k0 = (bid >> 2) * 64, n0 = (bid & 3) * 64;
        for (int i = 0; i < 16; ++i) {
            int r = i * 4 + w;
            tile[r][lane] = sw1[(size_t)(k0 + r) * 256 + n0 + lane];
        }
        __syncthreads();
        for (int i = 0; i < 16; ++i) {
            int c = i * 4 + w;
            wcat[(size_t)(n0 + c) * FH + k0 + lane] = (_Float16)tile[lane][c];
        }
    } else {
        int k0 = (bid - 512) * 64;
        int t = threadIdx.x;
        for (int i = 0; i < 8; ++i) {
            int idx = t + i * 256;
            int r = idx >> 5, cc = idx & 31;
            tile[r][cc] = ssw[(size_t)(k0 + r) * 32 + cc];
        }
        __syncthreads();
        for (int i = 0; i < 8; ++i) {
            int idx = t + i * 256;
            int c = idx >> 6, rr = idx & 63;
            wcat[(size_t)(256 + c) * FH + k0 + rr] = (_Float16)tile[rr][c];
        }
    }
}

// ---------------------------------------------------------------------------
// grn gemm stage with global_load_lds + XOR swizzle.
// Bs layout: 256 rows x 64 fp16 (unpadded). Row n, LDS chunk-pos cp (16B units)
// holds source chunk c = cp ^ (n&7). Fragment read for k-chunk (4*ks+q) of row
// n reads cp = (4*ks+q) ^ (n&7).
// ---------------------------------------------------------------------------
__device__ __forceinline__ void gemm_stage(
    const _Float16* __restrict__ Bsrc,   // weight slice for this f: [n][k], k contig
    const _Float16* As, _Float16* Bs,
    int t, int wv, int ln, int q, float4v acc[2][4])
{
    for (int kc = 0; kc < 4; ++kc) {
        __syncthreads();
#pragma unroll
        for (int it = 0; it < 8; ++it) {
            int s = it * 256 + t;          // LDS slot (wave-contiguous)
            int n = s >> 3;
            int c = (s & 7) ^ (n & 7);     // source chunk (xor swizzle)
            GLD_LDS(Bsrc + n * 256 + kc * 64 + c * 8, Bs + s * 8);
        }
        __syncthreads();
        for (int ks = 0; ks < 2; ++ks) {
            int kb = kc * 64 + ks * 32 + q * 8;
            half8 a0 = *(const half8*)&As[(0 + ln) * 264 + kb];
            half8 a1 = *(const half8*)&As[(16 + ln) * 264 + kb];
#pragma unroll
            for (int nt = 0; nt < 4; ++nt) {
                int n = wv * 64 + nt * 16 + ln;
                int cp = (ks * 4 + q) ^ (n & 7);
                half8 b8 = *(const half8*)&Bs[n * 64 + cp * 8];
                acc[0][nt] = __builtin_amdgcn_mfma_f32_16x16x32_f16(a0, b8, acc[0][nt], 0, 0, 0);
                acc[1][nt] = __builtin_amdgcn_mfma_f32_16x16x32_f16(a1, b8, acc[1][nt], 0, 0, 0);
            }
        }
    }
}

// ---------------------------------------------------------------------------
// Fused per-feature GRN: 3 GEMMs (K=256) + GLU + residual + LayerNorm
// One block = 32 tokens x one feature f. stacked written fp16 (chunk-local).
// ---------------------------------------------------------------------------
__global__ __launch_bounds__(256) void grn_kernel(
    const float* __restrict__ x, const float* __restrict__ w1, const float* __restrict__ b1,
    const float* __restrict__ b2, const float* __restrict__ bg, const float* __restrict__ bfv_,
    const float* __restrict__ gamma, const float* __restrict__ beta,
    const float* __restrict__ wsk, const float* __restrict__ bsk,
    const _Float16* __restrict__ w2t, const _Float16* __restrict__ wgt,
    const _Float16* __restrict__ wft, _Float16* __restrict__ stacked, int tok_base)
{
    __shared__ __align__(16) char smem[53248];
    _Float16* As = (_Float16*)smem;                     // 32 x 264 fp16
    float* xs = (float*)(smem + 16896);                 // 32
    _Float16* Bs = (_Float16*)(smem + 17024);           // 256 x 64 fp16 (swizzled)
    float* ys = (float*)(smem + 17024);                 // 32 x 265 f32 (alias Bs)
    float* red = (float*)(smem + 17024 + 33920);        // 512
    float* mv = (float*)(smem + 17024 + 33920 + 2048);  // 64

    const int f = blockIdx.y;
    const int tok0 = blockIdx.x * 32;                   // chunk-local
    const int t = threadIdx.x;
    const int wv = t >> 6;
    const int ln = t & 15;
    const int q = (t & 63) >> 4;

    if (t < 32) xs[t] = x[(size_t)(tok_base + tok0 + t) * F + f];
    __syncthreads();

    // A = elu(x * w1 + b1), fp16 into LDS (32 x 256, stride 264)
    {
        float w1v = w1[f * H + t];
        float b1v = b1[f * H + t];
#pragma unroll 4
        for (int i = 0; i < 32; ++i) {
            float z = xs[i] * w1v + b1v;
            float e = z > 0.f ? z : (expf(z) - 1.f);
            As[i * 264 + t] = (_Float16)e;
        }
    }
    // stage 1: h2 = A @ w2 + b2
    float4v acc1[2][4];
#pragma unroll
    for (int mt = 0; mt < 2; ++mt)
#pragma unroll
        for (int nt = 0; nt < 4; ++nt)
#pragma unroll
            for (int r = 0; r < 4; ++r) acc1[mt][nt][r] = 0.f;
    gemm_stage(w2t + (size_t)f * 65536, As, Bs, t, wv, ln, q, acc1);

    __syncthreads();  // all stage-1 MFMA reads of As done
    {
        const float* b2f = b2 + f * H;
#pragma unroll
        for (int mt = 0; mt < 2; ++mt)
#pragma unroll
            for (int nt = 0; nt < 4; ++nt) {
                int n = wv * 64 + nt * 16 + ln;
                float b2v = b2f[n];
#pragma unroll
                for (int r = 0; r < 4; ++r) {
                    int m = mt * 16 + q * 4 + r;
                    As[m * 264 + n] = (_Float16)(acc1[mt][nt][r] + b2v);
                }
            }
    }
    // stage 2: Cg = h2 @ wg, Cf = h2 @ wf (sequential, reuse Bs)
    float4v accG[2][4], accF[2][4];
#pragma unroll
    for (int mt = 0; mt < 2; ++mt)
#pragma unroll
        for (int nt = 0; nt < 4; ++nt)
#pragma unroll
            for (int r = 0; r < 4; ++r) { accG[mt][nt][r] = 0.f; accF[mt][nt][r] = 0.f; }
    gemm_stage(wgt + (size_t)f * 65536, As, Bs, t, wv, ln, q, accG);
    gemm_stage(wft + (size_t)f * 65536, As, Bs, t, wv, ln, q, accF);

    // epilogue: y = sigmoid(Cg+bg)*(Cf+bf) + x*ws + bs, into LDS f32
    __syncthreads();
    {
        const float* bgf = bg + f * H;
        const float* bff = bfv_ + f * H;
        const float* wsf = wsk + f * H;
        const float* bsf = bsk + f * H;
#pragma unroll
        for (int mt = 0; mt < 2; ++mt)
#pragma unroll
            for (int nt = 0; nt < 4; ++nt) {
                int n = wv * 64 + nt * 16 + ln;
                float bgv = bgf[n], bfv = bff[n], wsv = wsf[n], bsv = bsf[n];
#pragma unroll
                for (int r = 0; r < 4; ++r) {
                    int m = mt * 16 + q * 4 + r;
                    float cg = accG[mt][nt][r] + bgv;
                    float cf = accF[mt][nt][r] + bfv;
                    float sig = 1.f / (1.f + expf(-cg));
                    ys[m * 265 + n] = sig * cf + xs[m] * wsv + bsv;
                }
            }
    }
    __syncthreads();
    // LayerNorm over H=256 per row. Read pattern j*8+seg: 8 lanes of a row hit
    // 8 consecutive banks (was seg*32+j: 8-way same-bank conflict).
    {
        int row = t >> 3, seg = t & 7;
        float s1 = 0.f, s2 = 0.f;
#pragma unroll 8
        for (int j = 0; j < 32; ++j) {
            float v = ys[row * 265 + j * 8 + seg];
            s1 += v; s2 += v * v;
        }
        red[t] = s1; red[256 + t] = s2;
    }
    __syncthreads();
    if (t < 32) {
        float a = 0.f, b = 0.f;
        for (int s = 0; s < 8; ++s) { a += red[t * 8 + s]; b += red[256 + t * 8 + s]; }
        float mean = a * (1.f / 256.f);
        float var = b * (1.f / 256.f) - mean * mean;
        mv[t] = mean;
        mv[32 + t] = rsqrtf(var + 1e-5f);
    }
    __syncthreads();
    {
        float gv = gamma[f * H + t], bv = beta[f * H + t];
        for (int i = 0; i < 32; ++i) {
            float v = (ys[i * 265 + t] - mv[i]) * mv[32 + i] * gv + bv;
            stacked[(size_t)(tok0 + i) * FH + f * H + t] = (_Float16)v;
        }
    }
}

// ---------------------------------------------------------------------------
// Selection GEMM v3: BM=64, BK=64, 256 threads (4 waves, one n-column each).
// A (stacked) double-buffered in LDS via global_load_lds with XOR swizzle
// (row stride 64 fp16 = 128B; chunk cp holds source chunk cp^(row&7)).
// B (wcat, 4.5 MB, L2-resident) loaded straight to registers each K-step,
// ISSUED BEFORE the A-prefetch so counted vmcnt serves B without draining
// the prefetch. ALL accumulator indexing is compile-time static (rule #20:
// the previous runtime-NT loop put acc[][] in scratch -> every MFMA did a
// 1KB/wave scratch RMW; that was the phantom 2-4 GB of HBM traffic).
// 18 n-tiles: tiles 0..3 per wave static, tile 4 on waves 0,1 (wave-uniform
// branch); tile 4 is exactly the sres columns, so the n<256 test is static.
// ---------------------------------------------------------------------------
__global__ __launch_bounds__(256, 3) void sel_gemm_kernel(
    const _Float16* __restrict__ stacked, const _Float16* __restrict__ wcat,
    float* __restrict__ sh_part, float* __restrict__ sres_part, int C)
{
    __shared__ __align__(16) _Float16 As2[2][64 * 64];   // 2 x 8 KB
    const int t = threadIdx.x;
    const int wv = t >> 6;
    const int ln = t & 15, q = (t & 63) >> 4;
    const int tok0 = blockIdx.x * 64;                    // chunk-local
    const int kb = blockIdx.y;                           // k-slice 0..3

    // A staging: 512 slots (64 rows x 8 chunks), 2 per thread. Linear LDS
    // dest, inverse-swizzled global source (both-sides-or-neither, rule #21).
    const int s1 = t + 256;
    const int row0 = t >> 3,  c0 = ((t & 7) ^ (row0 & 7)) * 8;
    const int row1 = s1 >> 3, c1 = ((s1 & 7) ^ (row1 & 7)) * 8;
    const _Float16* a0src = stacked + (size_t)(tok0 + row0) * FH + kb * 2048 + c0;
    const _Float16* a1src = stacked + (size_t)(tok0 + row1) * FH + kb * 2048 + c1;

    float4v acc[4][5];
#pragma unroll
    for (int mt = 0; mt < 4; ++mt)
#pragma unroll
        for (int i = 0; i < 5; ++i)
#pragma unroll
            for (int r = 0; r < 4; ++r) acc[mt][i][r] = 0.f;

    GLD_LDS(a0src, &As2[0][t * 8]);
    GLD_LDS(a1src, &As2[0][s1 * 8]);
    __syncthreads();

    for (int kc = 0; kc < 32; ++kc) {
        const int cur = kc & 1;
        // ---- B fragments for this K-step: global->reg, issued FIRST ----
        half8 bb0[5], bb1[5];
#define SEL_LOAD(i)                                                            \
        {                                                                      \
            const _Float16* bp = wcat                                          \
                + (size_t)((wv + 4 * (i)) * 16 + ln) * FH                      \
                + kb * 2048 + kc * 64 + q * 8;                                 \
            bb0[i] = *(const half8*)bp;                                        \
            bb1[i] = *(const half8*)(bp + 32);                                 \
        }
        SEL_LOAD(0) SEL_LOAD(1) SEL_LOAD(2) SEL_LOAD(3)
        if (wv < 2) SEL_LOAD(4)
#undef SEL_LOAD
        // ---- prefetch next A tile into the other buffer ----
        if (kc < 31) {
            GLD_LDS(a0src + (kc + 1) * 64, &As2[cur ^ 1][t * 8]);
            GLD_LDS(a1src + (kc + 1) * 64, &As2[cur ^ 1][s1 * 8]);
        }
        // ---- A fragments from LDS (swizzled, conflict-free) ----
        const _Float16* As = As2[cur];
        half8 af0[4], af1[4];
#pragma unroll
        for (int mt = 0; mt < 4; ++mt) {
            int row = mt * 16 + ln;
            af0[mt] = *(const half8*)&As[row * 64 + ((q ^ (row & 7)) * 8)];
            af1[mt] = *(const half8*)&As[row * 64 + (((4 + q) ^ (row & 7)) * 8)];
        }
        // ---- MFMA, fully static indexing ----
#define SEL_FMA(i)                                                             \
        {                                                                      \
            _Pragma("unroll")                                                  \
            for (int mt = 0; mt < 4; ++mt)                                     \
                acc[mt][i] = __builtin_amdgcn_mfma_f32_16x16x32_f16(           \
                    af0[mt], bb0[i], acc[mt][i], 0, 0, 0);                     \
            _Pragma("unroll")                                                  \
            for (int mt = 0; mt < 4; ++mt)                                     \
                acc[mt][i] = __builtin_amdgcn_mfma_f32_16x16x32_f16(           \
                    af1[mt], bb1[i], acc[mt][i], 0, 0, 0);                     \
        }
        SEL_FMA(0) SEL_FMA(1) SEL_FMA(2) SEL_FMA(3)
        if (wv < 2) SEL_FMA(4)
#undef SEL_FMA
        __syncthreads();   // drains prefetch; all waves done reading buf[cur]
    }

    // ---- epilogue: plain stores, static branches ----
    float* shp = sh_part + (size_t)kb * ((size_t)C * 256);
    float* srp = sres_part + (size_t)kb * ((size_t)C * 32);
#pragma unroll
    for (int i = 0; i < 4; ++i) {
        int n = (wv + 4 * i) * 16 + ln;                  // always < 256
#pragma unroll
        for (int mt = 0; mt < 4; ++mt)
#pragma unroll
            for (int r = 0; r < 4; ++r) {
                int m = tok0 + mt * 16 + q * 4 + r;
                shp[(size_t)m * 256 + n] = acc[mt][i][r];
            }
    }
    if (wv < 2) {                                        // tile 4 = sres cols
        int n = wv * 16 + ln;                            // 0..31
#pragma unroll
        for (int mt = 0; mt < 4; ++mt)
#pragma unroll
            for (int r = 0; r < 4; ++r) {
                int m = tok0 + mt * 16 + q * 4 + r;
                srp[(size_t)m * 32 + n] = acc[mt][4][r];
            }
    }
}

// ---------------------------------------------------------------------------
// Fused selection tail + weighted sum. Block = 8 tokens (32 lanes each).
// Reduces the 4 split-K partials (+bias) -> elu -> fc2(256->32) -> GLU -> LN
// -> softmax -> out = sum_f stacked*w
// ---------------------------------------------------------------------------
__global__ __launch_bounds__(256) void tail_kernel(
    const float* __restrict__ sh_part, const float* __restrict__ sres_part,
    const _Float16* __restrict__ stacked,
    const float* __restrict__ sb1, const float* __restrict__ ssb,
    const float* __restrict__ sw2, const float* __restrict__ sb2,
    const float* __restrict__ swg, const float* __restrict__ sbg,
    const float* __restrict__ swf, const float* __restrict__ sbf,
    const float* __restrict__ sgam, const float* __restrict__ sbet,
    float* __restrict__ out, int tok_base, int C)
{
    __shared__ float sw2s[256 * 32];                    // 32 KB
    __shared__ float swgs[1024], swfs[1024];            // 8 KB
    __shared__ float shv[8][257];                       // 8 tokens x 256 (+pad)
    __shared__ float wls[8][33];
    const int t = threadIdx.x;
    const size_t shS = (size_t)C * 256;
    const size_t srS = (size_t)C * 32;
    for (int i = 0; i < 32; ++i) sw2s[t + i * 256] = sw2[t + i * 256];
    for (int i = 0; i < 4; ++i) {
        swgs[t + i * 256] = swg[t + i * 256];
        swfs[t + i * 256] = swf[t + i * 256];
    }
    // reduce split-K partials + bias, elu, stage for 8 tokens
    for (int i = 0; i < 8; ++i) {
        int idx = t + i * 256;
        int gg = idx >> 8, col = idx & 255;
        size_t o = (size_t)(blockIdx.x * 8 + gg) * 256 + col;
        float z = sb1[col] + sh_part[o] + sh_part[shS + o]
                + sh_part[2 * shS + o] + sh_part[3 * shS + o];
        shv[gg][col] = z > 0.f ? z : (expf(z) - 1.f);
    }
    __syncthreads();
    const int g = t >> 5;                               // token group 0..7
    const int j = t & 31;                               // feature index
    const int token = blockIdx.x * 8 + g;               // chunk-local
    // fc2: 256 -> 32
    float p = sb2[j];
    for (int k = 0; k < 256; ++k) p += shv[g][k] * sw2s[k * 32 + j];
    // GLU via width-32 shuffles
    float gacc = sbg[j], uacc = sbf[j];
#pragma unroll 8
    for (int i = 0; i < 32; ++i) {
        float tv = __shfl(p, i, 32);
        gacc += tv * swgs[i * 32 + j];
        uacc += tv * swfs[i * 32 + j];
    }
    float sig = 1.f / (1.f + expf(-gacc));
    size_t o2 = (size_t)token * 32 + j;
    float sresv = ssb[j] + sres_part[o2] + sres_part[srS + o2]
                + sres_part[2 * srS + o2] + sres_part[3 * srS + o2];
    float sv = sresv + sig * uacc;
    // LayerNorm over 32 lanes
    float s1 = sv, s2 = sv * sv;
    for (int off = 16; off; off >>= 1) {
        s1 += __shfl_xor(s1, off, 32);
        s2 += __shfl_xor(s2, off, 32);
    }
    float mean = s1 * (1.f / 32.f);
    float var = s2 * (1.f / 32.f) - mean * mean;
    float v = (sv - mean) * rsqrtf(var + 1e-5f) * sgam[j] + sbet[j];
    // softmax over 32 lanes
    float mx = v;
    for (int off = 16; off; off >>= 1) mx = fmaxf(mx, __shfl_xor(mx, off, 32));
    float e = expf(v - mx);
    float ssum = e;
    for (int off = 16; off; off >>= 1) ssum += __shfl_xor(ssum, off, 32);
    wls[g][j] = e / ssum;
    __syncthreads();
    // weighted sum over features for the block's 8 tokens
    for (int tk = 0; tk < 8; ++tk) {
        const _Float16* sp = stacked + (size_t)(blockIdx.x * 8 + tk) * FH;
        float a = 0.f;
#pragma unroll
        for (int f = 0; f < 32; ++f) a += (float)sp[f * 256 + t] * wls[tk][f];
        out[(size_t)(tok_base + blockIdx.x * 8 + tk) * 256 + t] = a;
    }
}

// ---------------------------------------------------------------------------
extern "C" void kernel_launch(void* const* d_in, const int* in_sizes, int n_in,
                              void* d_out, int out_size, void* d_ws, size_t ws_size,
                              hipStream_t stream)
{
    (void)in_sizes; (void)n_in; (void)out_size;
    const float* x    = (const float*)d_in[0];
    const float* w1   = (const float*)d_in[1];
    const float* b1   = (const float*)d_in[2];
    const float* w2   = (const float*)d_in[3];
    const float* b2   = (const float*)d_in[4];
    const float* wg   = (const float*)d_in[5];
    const float* bg   = (const float*)d_in[6];
    const float* wf   = (const float*)d_in[7];
    const float* bfp  = (const float*)d_in[8];
    const float* gamma= (const float*)d_in[9];
    const float* beta = (const float*)d_in[10];
    const float* wsk  = (const float*)d_in[11];
    const float* bsk  = (const float*)d_in[12];
    const float* sw1  = (const float*)d_in[13];
    const float* sb1  = (const float*)d_in[14];
    const float* sw2  = (const float*)d_in[15];
    const float* sb2  = (const float*)d_in[16];
    const float* swg  = (const float*)d_in[17];
    const float* sbg  = (const float*)d_in[18];
    const float* swf  = (const float*)d_in[19];
    const float* sbf  = (const float*)d_in[20];
    const float* sgam = (const float*)d_in[21];
    const float* sbet = (const float*)d_in[22];
    const float* ssw  = (const float*)d_in[23];
    const float* ssb  = (const float*)d_in[24];

    // ---- workspace layout, chunk size adaptive to ws_size ----
    // per-token: stacked 16384B + sh_part 4*1024B + sres_part 4*128B = 20992B
    const size_t fixedB = 12582912 + 4718592;            // wt (12 MiB) + wcat (4.5 MiB)
    int C = BT;                                          // tokens per chunk
    while (C > 512) {
        size_t need = fixedB + (size_t)C * 20992;
        if (need <= ws_size) break;
        C >>= 1;
    }
    const int nChunks = BT / C;

    char* ws = (char*)d_ws;
    _Float16* wt      = (_Float16*)ws;                                   // 3 x 2M fp16
    _Float16* wcat    = (_Float16*)(ws + 12582912);                      // 288 x 8192 fp16
    char* p = ws + fixedB;
    _Float16* stacked = (_Float16*)p;            p += (size_t)C * FH * 2;
    float* sh_part    = (float*)p;               p += (size_t)C * 256 * 4 * SPLITK;
    float* sres_part  = (float*)p;
    float* out        = (float*)d_out;

    hipLaunchKernelGGL(transpose_w_kernel, dim3(1536), dim3(256), 0, stream, w2, wg, wf, wt);
    hipLaunchKernelGGL(transpose_s_kernel, dim3(640), dim3(256), 0, stream, sw1, ssw, wcat);
    for (int c = 0; c < nChunks; ++c) {
        int tb = c * C;
        hipLaunchKernelGGL(grn_kernel, dim3(C / 32, 32), dim3(256), 0, stream,
                           x, w1, b1, b2, bg, bfp, gamma, beta, wsk, bsk,
                           wt, wt + 2097152, wt + 2 * 2097152, stacked, tb);
        hipLaunchKernelGGL(sel_gemm_kernel, dim3(C / 64, SPLITK), dim3(256), 0, stream,
                           stacked, wcat, sh_part, sres_part, C);
        hipLaunchKernelGGL(tail_kernel, dim3(C / 8), dim3(256), 0, stream,
                           sh_part, sres_part, stacked, sb1, ssb, sw2, sb2, swg, sbg, swf, sbf,
                           sgam, sbet, out, tb, C);
    }
}

// Round 4
// 918.288 us; speedup vs baseline: 2.4729x; 1.1165x over previous
//
#include <hip/hip_runtime.h>
#include <hip/hip_bf16.h>
#include <hip/hip_fp16.h>

#define BT 16384
#define F 32
#define H 256
#define FH 8192
#define SPLITK 4

typedef _Float16 half8 __attribute__((ext_vector_type(8)));
typedef _Float16 half4v __attribute__((ext_vector_type(4)));
typedef float float4v __attribute__((ext_vector_type(4)));

#define GLD_LDS(gsrc, ldst) \
    __builtin_amdgcn_global_load_lds( \
        (const __attribute__((address_space(1))) void*)(gsrc), \
        (__attribute__((address_space(3))) void*)(ldst), 16, 0, 0)

// Pipelined-barrier macros (T3/T4): counted vmcnt keeps the prefetch in
// flight ACROSS the barrier; sched_barrier(0) pins ordering (rule #18).
#define WAITVM4_BAR() do { \
    __builtin_amdgcn_sched_barrier(0); \
    asm volatile("s_waitcnt vmcnt(4)" ::: "memory"); \
    __builtin_amdgcn_s_barrier(); \
    __builtin_amdgcn_sched_barrier(0); } while (0)
#define WAITVM0_BAR() do { \
    __builtin_amdgcn_sched_barrier(0); \
    asm volatile("s_waitcnt vmcnt(0)" ::: "memory"); \
    __builtin_amdgcn_s_barrier(); \
    __builtin_amdgcn_sched_barrier(0); } while (0)
#define END_BAR() do { \
    __builtin_amdgcn_sched_barrier(0); \
    __builtin_amdgcn_s_barrier(); \
    __builtin_amdgcn_sched_barrier(0); } while (0)
#define LGKM_BAR() do { \
    __builtin_amdgcn_sched_barrier(0); \
    asm volatile("s_waitcnt lgkmcnt(0)" ::: "memory"); \
    __builtin_amdgcn_s_barrier(); \
    __builtin_amdgcn_sched_barrier(0); } while (0)

// ---------------------------------------------------------------------------
// Prep: transpose w2/wg/wf (F,H_contr,H_out) fp32 -> [f][n_out][h_contr] fp16
// ---------------------------------------------------------------------------
__global__ __launch_bounds__(256) void transpose_w_kernel(
    const float* __restrict__ w2, const float* __restrict__ wg,
    const float* __restrict__ wf, _Float16* __restrict__ wt)
{
    __shared__ float tile[64][65];
    int bid = blockIdx.x;
    int tens = bid >> 9, rem = bid & 511;
    int f = rem >> 4, tl = rem & 15;
    int hb = (tl >> 2) * 64, nb = (tl & 3) * 64;
    const float* src = (tens == 0 ? w2 : (tens == 1 ? wg : wf)) + f * 65536;
    _Float16* dst = wt + (size_t)tens * 2097152 + f * 65536;
    int lane = threadIdx.x & 63, w = threadIdx.x >> 6;
    for (int i = 0; i < 16; ++i) {
        int r = i * 4 + w;
        tile[r][lane] = src[(hb + r) * 256 + nb + lane];
    }
    __syncthreads();
    for (int i = 0; i < 16; ++i) {
        int c = i * 4 + w;
        dst[(nb + c) * 256 + hb + lane] = (_Float16)tile[lane][c];
    }
}

// ---------------------------------------------------------------------------
// Prep: Wcat[n][k] fp16, n<256 from sw1 (8192,256), n in [256,288) from ssw
// ---------------------------------------------------------------------------
__global__ __launch_bounds__(256) void transpose_s_kernel(
    const float* __restrict__ sw1, const float* __restrict__ ssw,
    _Float16* __restrict__ wcat)
{
    __shared__ float tile[64][65];
    int bid = blockIdx.x;
    int lane = threadIdx.x & 63, w = threadIdx.x >> 6;
    if (bid < 512) {
        int k0 = (bid >> 2) * 64, n0 = (bid & 3) * 64;
        for (int i = 0; i < 16; ++i) {
            int r = i * 4 + w;
            tile[r][lane] = sw1[(size_t)(k0 + r) * 256 + n0 + lane];
        }
        __syncthreads();
        for (int i = 0; i < 16; ++i) {
            int c = i * 4 + w;
            wcat[(size_t)(n0 + c) * FH + k0 + lane] = (_Float16)tile[lane][c];
        }
    } else {
        int k0 = (bid - 512) * 64;
        int t = threadIdx.x;
        for (int i = 0; i < 8; ++i) {
            int idx = t + i * 256;
            int r = idx >> 5, cc = idx & 31;
            tile[r][cc] = ssw[(size_t)(k0 + r) * 32 + cc];
        }
        __syncthreads();
        for (int i = 0; i < 8; ++i) {
            int idx = t + i * 256;
            int c = idx >> 6, rr = idx & 63;
            wcat[(size_t)(256 + c) * FH + k0 + rr] = (_Float16)tile[rr][c];
        }
    }
}

// ---------------------------------------------------------------------------
// Fused per-feature GRN v2: 3 GEMMs (K=256) pipelined as one continuous
// 24-step ping-pong (BK=32, 2x16KB Bs buffers). Per step: issue next-tile
// global_load_lds FIRST, s_waitcnt vmcnt(4)+barrier (prefetch survives the
// barrier), 8 MFMA, bare barrier. Prefetch chains across w2->wg->wf stage
// boundaries; the h2 epilogue uses an lgkmcnt-only barrier so the wg-kc0
// tile stays in flight. Numerically identical to v1 (same K order).
// Bs swizzle: slot s (row=s>>2, pos=s&3) holds source chunk (s&3)^(row&3);
// reader of k-chunk q reads pos q^(row&3).
// ys stride 264 f32 + XOR mask ((m>>2)&3)<<3 on the element index: GLU
// write 2-way max, LN reads clean, and the final read is an aligned b128.
// ---------------------------------------------------------------------------
__global__ __launch_bounds__(256) void grn_kernel(
    const float* __restrict__ x, const float* __restrict__ w1, const float* __restrict__ b1,
    const float* __restrict__ b2, const float* __restrict__ bg, const float* __restrict__ bfv_,
    const float* __restrict__ gamma, const float* __restrict__ beta,
    const float* __restrict__ wsk, const float* __restrict__ bsk,
    const _Float16* __restrict__ w2t, const _Float16* __restrict__ wgt,
    const _Float16* __restrict__ wft, _Float16* __restrict__ stacked, int tok_base)
{
    __shared__ __align__(16) char smem[53248];
    _Float16* As = (_Float16*)smem;                     // 32 x 264 fp16
    float* xs = (float*)(smem + 16896);                 // 32
    _Float16* Bs = (_Float16*)(smem + 17024);           // 2 x (256 x 32) fp16
    float* ys = (float*)(smem + 17024);                 // 32 x 264 f32 (alias Bs)
    float* red = (float*)(smem + 17024 + 33920);        // 512
    float* mv = (float*)(smem + 17024 + 33920 + 2048);  // 64

    const int f = blockIdx.y;
    const int tok0 = blockIdx.x * 32;                   // chunk-local
    const int t = threadIdx.x;
    const int wv = t >> 6;
    const int ln = t & 15;
    const int q = (t & 63) >> 4;

    const _Float16* w2f = w2t + (size_t)f * 65536;
    const _Float16* wgf = wgt + (size_t)f * 65536;
    const _Float16* wff = wft + (size_t)f * 65536;

    // 4 staging slots per thread: s = t + i*256; row = s>>2, pos = s&3,
    // source chunk c = pos ^ (row&3). LDS dest is lane-contiguous 16B.
#define GRN_STAGE(buf, Bsrc, kc) do {                                          \
        const _Float16* _bp = (Bsrc);                                          \
        _Pragma("unroll")                                                      \
        for (int _i = 0; _i < 4; ++_i) {                                       \
            int _s = t + _i * 256;                                             \
            int _row = _s >> 2;                                                \
            int _c = (_s & 3) ^ (_row & 3);                                    \
            GLD_LDS(_bp + _row * 256 + (kc) * 32 + _c * 8,                     \
                    Bs + (buf) * 8192 + _s * 8);                               \
        } } while (0)

#define GRN_MFMA(ACC, kc) do {                                                 \
        const _Float16* _B = Bs + ((kc) & 1) * 8192;                           \
        half8 _a0 = *(const half8*)&As[ln * 264 + (kc) * 32 + q * 8];          \
        half8 _a1 = *(const half8*)&As[(16 + ln) * 264 + (kc) * 32 + q * 8];   \
        _Pragma("unroll")                                                      \
        for (int _nt = 0; _nt < 4; ++_nt) {                                    \
            int _row = wv * 64 + _nt * 16 + ln;                                \
            int _cp = q ^ (_row & 3);                                          \
            half8 _b8 = *(const half8*)&_B[_row * 32 + _cp * 8];               \
            ACC[0][_nt] = __builtin_amdgcn_mfma_f32_16x16x32_f16(              \
                _a0, _b8, ACC[0][_nt], 0, 0, 0);                               \
            ACC[1][_nt] = __builtin_amdgcn_mfma_f32_16x16x32_f16(              \
                _a1, _b8, ACC[1][_nt], 0, 0, 0);                               \
        } } while (0)

    // prologue: xs load first (oldest in vm FIFO), then first weight tile
    if (t < 32) xs[t] = x[(size_t)(tok_base + tok0 + t) * F + f];
    GRN_STAGE(0, w2f, 0);
    LGKM_BAR();                                          // xs visible; stage stays in flight

    // A = elu(x * w1 + b1), fp16 into LDS (32 x 256, stride 264)
    {
        float w1v = w1[f * H + t];
        float b1v = b1[f * H + t];
#pragma unroll 4
        for (int i = 0; i < 32; ++i) {
            float z = xs[i] * w1v + b1v;
            float e = z > 0.f ? z : (expf(z) - 1.f);
            As[i * 264 + t] = (_Float16)e;
        }
    }
    LGKM_BAR();                                          // As visible

    float4v acc1[2][4];
#pragma unroll
    for (int mt = 0; mt < 2; ++mt)
#pragma unroll
        for (int nt = 0; nt < 4; ++nt)
#pragma unroll
            for (int r = 0; r < 4; ++r) acc1[mt][nt][r] = 0.f;

    // ---- stage 1: h2 = A @ w2 ----
#pragma unroll
    for (int kc = 0; kc < 8; ++kc) {
        if (kc < 7) GRN_STAGE((kc + 1) & 1, w2f, kc + 1);
        else        GRN_STAGE(0, wgf, 0);                // chain into stage 2
        WAITVM4_BAR();
        GRN_MFMA(acc1, kc);
        END_BAR();
    }

    // h2 + b2 -> As (fp16). wg kc0 tile is in flight; lgkm-only barrier.
    {
        const float* b2f = b2 + f * H;
#pragma unroll
        for (int mt = 0; mt < 2; ++mt)
#pragma unroll
            for (int nt = 0; nt < 4; ++nt) {
                int n = wv * 64 + nt * 16 + ln;
                float b2v = b2f[n];
#pragma unroll
                for (int r = 0; r < 4; ++r) {
                    int m = mt * 16 + q * 4 + r;
                    As[m * 264 + n] = (_Float16)(acc1[mt][nt][r] + b2v);
                }
            }
    }
    LGKM_BAR();

    float4v accG[2][4], accF[2][4];
#pragma unroll
    for (int mt = 0; mt < 2; ++mt)
#pragma unroll
        for (int nt = 0; nt < 4; ++nt)
#pragma unroll
            for (int r = 0; r < 4; ++r) { accG[mt][nt][r] = 0.f; accF[mt][nt][r] = 0.f; }

    // ---- stage 2a: Cg = h2 @ wg ----
#pragma unroll
    for (int kc = 0; kc < 8; ++kc) {
        if (kc < 7) GRN_STAGE((kc + 1) & 1, wgf, kc + 1);
        else        GRN_STAGE(0, wff, 0);                // chain into wf
        WAITVM4_BAR();
        GRN_MFMA(accG, kc);
        END_BAR();
    }
    // ---- stage 2b: Cf = h2 @ wf ----
#pragma unroll
    for (int kc = 0; kc < 8; ++kc) {
        if (kc < 7) {
            GRN_STAGE((kc + 1) & 1, wff, kc + 1);
            WAITVM4_BAR();
        } else {
            WAITVM0_BAR();                               // final drain
        }
        GRN_MFMA(accF, kc);
        END_BAR();
    }
#undef GRN_STAGE
#undef GRN_MFMA

    // epilogue: y = sigmoid(Cg+bg)*(Cf+bf) + x*ws + bs, into LDS f32
    // ys[m][n] stored at m*264 + (n ^ ((m>>2 & 3)<<3))
    {
        const float* bgf = bg + f * H;
        const float* bff = bfv_ + f * H;
        const float* wsf = wsk + f * H;
        const float* bsf = bsk + f * H;
#pragma unroll
        for (int mt = 0; mt < 2; ++mt)
#pragma unroll
            for (int nt = 0; nt < 4; ++nt) {
                int n = wv * 64 + nt * 16 + ln;
                float bgv = bgf[n], bfv = bff[n], wsv = wsf[n], bsv = bsf[n];
#pragma unroll
                for (int r = 0; r < 4; ++r) {
                    int m = mt * 16 + q * 4 + r;
                    float cg = accG[mt][nt][r] + bgv;
                    float cf = accF[mt][nt][r] + bfv;
                    float sig = 1.f / (1.f + expf(-cg));
                    ys[m * 264 + (n ^ (((m >> 2) & 3) << 3))] =
                        sig * cf + xs[m] * wsv + bsv;
                }
            }
    }
    __syncthreads();
    // LayerNorm sums over H=256 per row (8 segments of 32 per row)
    {
        int row = t >> 3, seg = t & 7;
        int msk = ((row >> 2) & 3) << 3;
        float s1 = 0.f, s2 = 0.f;
#pragma unroll 8
        for (int j = 0; j < 32; ++j) {
            float v = ys[row * 264 + ((j * 8 + seg) ^ msk)];
            s1 += v; s2 += v * v;
        }
        red[t] = s1; red[256 + t] = s2;
    }
    __syncthreads();
    if (t < 32) {
        float a = 0.f, b = 0.f;
        for (int s = 0; s < 8; ++s) { a += red[t * 8 + s]; b += red[256 + t * 8 + s]; }
        float mean = a * (1.f / 256.f);
        float var = b * (1.f / 256.f) - mean * mean;
        mv[t] = mean;
        mv[32 + t] = rsqrtf(var + 1e-5f);
    }
    __syncthreads();
    // normalize + scale, vectorized: each lane owns 4 consecutive cols of
    // 8 rows -> aligned b128 ys read, 8B global store.
    {
        const int c4 = (t & 63) * 4;
        float4v gv = *(const float4v*)&gamma[f * H + c4];
        float4v bv = *(const float4v*)&beta[f * H + c4];
#pragma unroll
        for (int i = 0; i < 8; ++i) {
            int row = wv * 8 + i;
            int msk = ((row >> 2) & 3) << 3;
            float4v yv = *(const float4v*)&ys[row * 264 + (c4 ^ msk)];
            float m_ = mv[row], r_ = mv[32 + row];
            half4v o;
#pragma unroll
            for (int j = 0; j < 4; ++j)
                o[j] = (_Float16)((yv[j] - m_) * r_ * gv[j] + bv[j]);
            *(half4v*)&stacked[(size_t)(tok0 + row) * FH + f * H + c4] = o;
        }
    }
}

// ---------------------------------------------------------------------------
// Selection GEMM v3: BM=64, BK=64, 256 threads (4 waves, one n-column each).
// A (stacked) double-buffered in LDS via global_load_lds with XOR swizzle.
// B (wcat, L2-resident) loaded straight to registers each K-step. All
// accumulator indexing compile-time static (rule #20).
// ---------------------------------------------------------------------------
__global__ __launch_bounds__(256, 3) void sel_gemm_kernel(
    const _Float16* __restrict__ stacked, const _Float16* __restrict__ wcat,
    float* __restrict__ sh_part, float* __restrict__ sres_part, int C)
{
    __shared__ __align__(16) _Float16 As2[2][64 * 64];   // 2 x 8 KB
    const int t = threadIdx.x;
    const int wv = t >> 6;
    const int ln = t & 15, q = (t & 63) >> 4;
    const int tok0 = blockIdx.x * 64;                    // chunk-local
    const int kb = blockIdx.y;                           // k-slice 0..3

    const int s1 = t + 256;
    const int row0 = t >> 3,  c0 = ((t & 7) ^ (row0 & 7)) * 8;
    const int row1 = s1 >> 3, c1 = ((s1 & 7) ^ (row1 & 7)) * 8;
    const _Float16* a0src = stacked + (size_t)(tok0 + row0) * FH + kb * 2048 + c0;
    const _Float16* a1src = stacked + (size_t)(tok0 + row1) * FH + kb * 2048 + c1;

    float4v acc[4][5];
#pragma unroll
    for (int mt = 0; mt < 4; ++mt)
#pragma unroll
        for (int i = 0; i < 5; ++i)
#pragma unroll
            for (int r = 0; r < 4; ++r) acc[mt][i][r] = 0.f;

    GLD_LDS(a0src, &As2[0][t * 8]);
    GLD_LDS(a1src, &As2[0][s1 * 8]);
    __syncthreads();

    for (int kc = 0; kc < 32; ++kc) {
        const int cur = kc & 1;
        // ---- B fragments for this K-step: global->reg, issued FIRST ----
        half8 bb0[5], bb1[5];
#define SEL_LOAD(i)                                                            \
        {                                                                      \
            const _Float16* bp = wcat                                          \
                + (size_t)((wv + 4 * (i)) * 16 + ln) * FH                      \
                + kb * 2048 + kc * 64 + q * 8;                                 \
            bb0[i] = *(const half8*)bp;                                        \
            bb1[i] = *(const half8*)(bp + 32);                                 \
        }
        SEL_LOAD(0) SEL_LOAD(1) SEL_LOAD(2) SEL_LOAD(3)
        if (wv < 2) SEL_LOAD(4)
#undef SEL_LOAD
        // ---- prefetch next A tile into the other buffer ----
        if (kc < 31) {
            GLD_LDS(a0src + (kc + 1) * 64, &As2[cur ^ 1][t * 8]);
            GLD_LDS(a1src + (kc + 1) * 64, &As2[cur ^ 1][s1 * 8]);
        }
        // ---- A fragments from LDS (swizzled, conflict-free) ----
        const _Float16* As = As2[cur];
        half8 af0[4], af1[4];
#pragma unroll
        for (int mt = 0; mt < 4; ++mt) {
            int row = mt * 16 + ln;
            af0[mt] = *(const half8*)&As[row * 64 + ((q ^ (row & 7)) * 8)];
            af1[mt] = *(const half8*)&As[row * 64 + (((4 + q) ^ (row & 7)) * 8)];
        }
        // ---- MFMA, fully static indexing ----
#define SEL_FMA(i)                                                             \
        {                                                                      \
            _Pragma("unroll")                                                  \
            for (int mt = 0; mt < 4; ++mt)                                     \
                acc[mt][i] = __builtin_amdgcn_mfma_f32_16x16x32_f16(           \
                    af0[mt], bb0[i], acc[mt][i], 0, 0, 0);                     \
            _Pragma("unroll")                                                  \
            for (int mt = 0; mt < 4; ++mt)                                     \
                acc[mt][i] = __builtin_amdgcn_mfma_f32_16x16x32_f16(           \
                    af1[mt], bb1[i], acc[mt][i], 0, 0, 0);                     \
        }
        SEL_FMA(0) SEL_FMA(1) SEL_FMA(2) SEL_FMA(3)
        if (wv < 2) SEL_FMA(4)
#undef SEL_FMA
        __syncthreads();   // drains prefetch; all waves done reading buf[cur]
    }

    // ---- epilogue: plain stores, static branches ----
    float* shp = sh_part + (size_t)kb * ((size_t)C * 256);
    float* srp = sres_part + (size_t)kb * ((size_t)C * 32);
#pragma unroll
    for (int i = 0; i < 4; ++i) {
        int n = (wv + 4 * i) * 16 + ln;                  // always < 256
#pragma unroll
        for (int mt = 0; mt < 4; ++mt)
#pragma unroll
            for (int r = 0; r < 4; ++r) {
                int m = tok0 + mt * 16 + q * 4 + r;
                shp[(size_t)m * 256 + n] = acc[mt][i][r];
            }
    }
    if (wv < 2) {                                        // tile 4 = sres cols
        int n = wv * 16 + ln;                            // 0..31
#pragma unroll
        for (int mt = 0; mt < 4; ++mt)
#pragma unroll
            for (int r = 0; r < 4; ++r) {
                int m = tok0 + mt * 16 + q * 4 + r;
                srp[(size_t)m * 32 + n] = acc[mt][4][r];
            }
    }
}

// ---------------------------------------------------------------------------
// Fused selection tail + weighted sum. Block = 8 tokens (32 lanes each).
// Reduces the 4 split-K partials (+bias) -> elu -> fc2(256->32) -> GLU -> LN
// -> softmax -> out = sum_f stacked*w
// ---------------------------------------------------------------------------
__global__ __launch_bounds__(256) void tail_kernel(
    const float* __restrict__ sh_part, const float* __restrict__ sres_part,
    const _Float16* __restrict__ stacked,
    const float* __restrict__ sb1, const float* __restrict__ ssb,
    const float* __restrict__ sw2, const float* __restrict__ sb2,
    const float* __restrict__ swg, const float* __restrict__ sbg,
    const float* __restrict__ swf, const float* __restrict__ sbf,
    const float* __restrict__ sgam, const float* __restrict__ sbet,
    float* __restrict__ out, int tok_base, int C)
{
    __shared__ float sw2s[256 * 32];                    // 32 KB
    __shared__ float swgs[1024], swfs[1024];            // 8 KB
    __shared__ float shv[8][257];                       // 8 tokens x 256 (+pad)
    __shared__ float wls[8][33];
    const int t = threadIdx.x;
    const size_t shS = (size_t)C * 256;
    const size_t srS = (size_t)C * 32;
    for (int i = 0; i < 32; ++i) sw2s[t + i * 256] = sw2[t + i * 256];
    for (int i = 0; i < 4; ++i) {
        swgs[t + i * 256] = swg[t + i * 256];
        swfs[t + i * 256] = swf[t + i * 256];
    }
    // reduce split-K partials + bias, elu, stage for 8 tokens
    for (int i = 0; i < 8; ++i) {
        int idx = t + i * 256;
        int gg = idx >> 8, col = idx & 255;
        size_t o = (size_t)(blockIdx.x * 8 + gg) * 256 + col;
        float z = sb1[col] + sh_part[o] + sh_part[shS + o]
                + sh_part[2 * shS + o] + sh_part[3 * shS + o];
        shv[gg][col] = z > 0.f ? z : (expf(z) - 1.f);
    }
    __syncthreads();
    const int g = t >> 5;                               // token group 0..7
    const int j = t & 31;                               // feature index
    const int token = blockIdx.x * 8 + g;               // chunk-local
    // fc2: 256 -> 32
    float p = sb2[j];
    for (int k = 0; k < 256; ++k) p += shv[g][k] * sw2s[k * 32 + j];
    // GLU via width-32 shuffles
    float gacc = sbg[j], uacc = sbf[j];
#pragma unroll 8
    for (int i = 0; i < 32; ++i) {
        float tv = __shfl(p, i, 32);
        gacc += tv * swgs[i * 32 + j];
        uacc += tv * swfs[i * 32 + j];
    }
    float sig = 1.f / (1.f + expf(-gacc));
    size_t o2 = (size_t)token * 32 + j;
    float sresv = ssb[j] + sres_part[o2] + sres_part[srS + o2]
                + sres_part[2 * srS + o2] + sres_part[3 * srS + o2];
    float sv = sresv + sig * uacc;
    // LayerNorm over 32 lanes
    float s1 = sv, s2 = sv * sv;
    for (int off = 16; off; off >>= 1) {
        s1 += __shfl_xor(s1, off, 32);
        s2 += __shfl_xor(s2, off, 32);
    }
    float mean = s1 * (1.f / 32.f);
    float var = s2 * (1.f / 32.f) - mean * mean;
    float v = (sv - mean) * rsqrtf(var + 1e-5f) * sgam[j] + sbet[j];
    // softmax over 32 lanes
    float mx = v;
    for (int off = 16; off; off >>= 1) mx = fmaxf(mx, __shfl_xor(mx, off, 32));
    float e = expf(v - mx);
    float ssum = e;
    for (int off = 16; off; off >>= 1) ssum += __shfl_xor(ssum, off, 32);
    wls[g][j] = e / ssum;
    __syncthreads();
    // weighted sum over features for the block's 8 tokens
    for (int tk = 0; tk < 8; ++tk) {
        const _Float16* sp = stacked + (size_t)(blockIdx.x * 8 + tk) * FH;
        float a = 0.f;
#pragma unroll
        for (int f = 0; f < 32; ++f) a += (float)sp[f * 256 + t] * wls[tk][f];
        out[(size_t)(tok_base + blockIdx.x * 8 + tk) * 256 + t] = a;
    }
}

// ---------------------------------------------------------------------------
extern "C" void kernel_launch(void* const* d_in, const int* in_sizes, int n_in,
                              void* d_out, int out_size, void* d_ws, size_t ws_size,
                              hipStream_t stream)
{
    (void)in_sizes; (void)n_in; (void)out_size;
    const float* x    = (const float*)d_in[0];
    const float* w1   = (const float*)d_in[1];
    const float* b1   = (const float*)d_in[2];
    const float* w2   = (const float*)d_in[3];
    const float* b2   = (const float*)d_in[4];
    const float* wg   = (const float*)d_in[5];
    const float* bg   = (const float*)d_in[6];
    const float* wf   = (const float*)d_in[7];
    const float* bfp  = (const float*)d_in[8];
    const float* gamma= (const float*)d_in[9];
    const float* beta = (const float*)d_in[10];
    const float* wsk  = (const float*)d_in[11];
    const float* bsk  = (const float*)d_in[12];
    const float* sw1  = (const float*)d_in[13];
    const float* sb1  = (const float*)d_in[14];
    const float* sw2  = (const float*)d_in[15];
    const float* sb2  = (const float*)d_in[16];
    const float* swg  = (const float*)d_in[17];
    const float* sbg  = (const float*)d_in[18];
    const float* swf  = (const float*)d_in[19];
    const float* sbf  = (const float*)d_in[20];
    const float* sgam = (const float*)d_in[21];
    const float* sbet = (const float*)d_in[22];
    const float* ssw  = (const float*)d_in[23];
    const float* ssb  = (const float*)d_in[24];

    // ---- workspace layout, chunk size adaptive to ws_size ----
    // per-token: stacked 16384B + sh_part 4*1024B + sres_part 4*128B = 20992B
    const size_t fixedB = 12582912 + 4718592;            // wt (12 MiB) + wcat (4.5 MiB)
    int C = BT;                                          // tokens per chunk
    while (C > 512) {
        size_t need = fixedB + (size_t)C * 20992;
        if (need <= ws_size) break;
        C >>= 1;
    }
    const int nChunks = BT / C;

    char* ws = (char*)d_ws;
    _Float16* wt      = (_Float16*)ws;                                   // 3 x 2M fp16
    _Float16* wcat    = (_Float16*)(ws + 12582912);                      // 288 x 8192 fp16
    char* p = ws + fixedB;
    _Float16* stacked = (_Float16*)p;            p += (size_t)C * FH * 2;
    float* sh_part    = (float*)p;               p += (size_t)C * 256 * 4 * SPLITK;
    float* sres_part  = (float*)p;
    float* out        = (float*)d_out;

    hipLaunchKernelGGL(transpose_w_kernel, dim3(1536), dim3(256), 0, stream, w2, wg, wf, wt);
    hipLaunchKernelGGL(transpose_s_kernel, dim3(640), dim3(256), 0, stream, sw1, ssw, wcat);
    for (int c = 0; c < nChunks; ++c) {
        int tb = c * C;
        hipLaunchKernelGGL(grn_kernel, dim3(C / 32, 32), dim3(256), 0, stream,
                           x, w1, b1, b2, bg, bfp, gamma, beta, wsk, bsk,
                           wt, wt + 2097152, wt + 2 * 2097152, stacked, tb);
        hipLaunchKernelGGL(sel_gemm_kernel, dim3(C / 64, SPLITK), dim3(256), 0, stream,
                           stacked, wcat, sh_part, sres_part, C);
        hipLaunchKernelGGL(tail_kernel, dim3(C / 8), dim3(256), 0, stream,
                           sh_part, sres_part, stacked, sb1, ssb, sw2, sb2, swg, sbg, swf, sbf,
                           sgam, sbet, out, tb, C);
    }
}

// Round 5
// 806.376 us; speedup vs baseline: 2.8161x; 1.1388x over previous
//
#include <hip/hip_runtime.h>
#include <hip/hip_bf16.h>
#include <hip/hip_fp16.h>

#define BT 16384
#define F 32
#define H 256
#define FH 8192
#define SPLITK 4

typedef _Float16 half8 __attribute__((ext_vector_type(8)));
typedef float float4v __attribute__((ext_vector_type(4)));

#define GLD_LDS(gsrc, ldst) \
    __builtin_amdgcn_global_load_lds( \
        (const __attribute__((address_space(1))) void*)(gsrc), \
        (__attribute__((address_space(3))) void*)(ldst), 16, 0, 0)

// Pipelined-barrier macros (T3/T4): counted vmcnt keeps the prefetch in
// flight ACROSS the barrier; sched_barrier(0) pins ordering (rule #18).
#define WAITVM2_BAR() do { \
    __builtin_amdgcn_sched_barrier(0); \
    asm volatile("s_waitcnt vmcnt(2)" ::: "memory"); \
    __builtin_amdgcn_s_barrier(); \
    __builtin_amdgcn_sched_barrier(0); } while (0)
#define WAITVM0_BAR() do { \
    __builtin_amdgcn_sched_barrier(0); \
    asm volatile("s_waitcnt vmcnt(0)" ::: "memory"); \
    __builtin_amdgcn_s_barrier(); \
    __builtin_amdgcn_sched_barrier(0); } while (0)
#define END_BAR() do { \
    __builtin_amdgcn_sched_barrier(0); \
    __builtin_amdgcn_s_barrier(); \
    __builtin_amdgcn_sched_barrier(0); } while (0)
#define LGKM_BAR() do { \
    __builtin_amdgcn_sched_barrier(0); \
    asm volatile("s_waitcnt lgkmcnt(0)" ::: "memory"); \
    __builtin_amdgcn_s_barrier(); \
    __builtin_amdgcn_sched_barrier(0); } while (0)

// ---------------------------------------------------------------------------
// Prep: transpose w2/wg/wf (F,H_contr,H_out) fp32 -> [f][n_out][h_contr] fp16
// ---------------------------------------------------------------------------
__global__ __launch_bounds__(256) void transpose_w_kernel(
    const float* __restrict__ w2, const float* __restrict__ wg,
    const float* __restrict__ wf, _Float16* __restrict__ wt)
{
    __shared__ float tile[64][65];
    int bid = blockIdx.x;
    int tens = bid >> 9, rem = bid & 511;
    int f = rem >> 4, tl = rem & 15;
    int hb = (tl >> 2) * 64, nb = (tl & 3) * 64;
    const float* src = (tens == 0 ? w2 : (tens == 1 ? wg : wf)) + f * 65536;
    _Float16* dst = wt + (size_t)tens * 2097152 + f * 65536;
    int lane = threadIdx.x & 63, w = threadIdx.x >> 6;
    for (int i = 0; i < 16; ++i) {
        int r = i * 4 + w;
        tile[r][lane] = src[(hb + r) * 256 + nb + lane];
    }
    __syncthreads();
    for (int i = 0; i < 16; ++i) {
        int c = i * 4 + w;
        dst[(nb + c) * 256 + hb + lane] = (_Float16)tile[lane][c];
    }
}

// ---------------------------------------------------------------------------
// Prep: Wcat[n][k] fp16, n<256 from sw1 (8192,256), n in [256,288) from ssw
// ---------------------------------------------------------------------------
__global__ __launch_bounds__(256) void transpose_s_kernel(
    const float* __restrict__ sw1, const float* __restrict__ ssw,
    _Float16* __restrict__ wcat)
{
    __shared__ float tile[64][65];
    int bid = blockIdx.x;
    int lane = threadIdx.x & 63, w = threadIdx.x >> 6;
    if (bid < 512) {
        int k0 = (bid >> 2) * 64, n0 = (bid & 3) * 64;
        for (int i = 0; i < 16; ++i) {
            int r = i * 4 + w;
            tile[r][lane] = sw1[(size_t)(k0 + r) * 256 + n0 + lane];
        }
        __syncthreads();
        for (int i = 0; i < 16; ++i) {
            int c = i * 4 + w;
            wcat[(size_t)(n0 + c) * FH + k0 + lane] = (_Float16)tile[lane][c];
        }
    } else {
        int k0 = (bid - 512) * 64;
        int t = threadIdx.x;
        for (int i = 0; i < 8; ++i) {
            int idx = t + i * 256;
            int r = idx >> 5, cc = idx & 31;
            tile[r][cc] = ssw[(size_t)(k0 + r) * 32 + cc];
        }
        __syncthreads();
        for (int i = 0; i < 8; ++i) {
            int idx = t + i * 256;
            int c = idx >> 6, rr = idx & 63;
            wcat[(size_t)(256 + c) * FH + k0 + rr] = (_Float16)tile[rr][c];
        }
    }
}

// ---------------------------------------------------------------------------
// Fused per-feature GRN v3: BM=64 tokens x 1 feature, 512 threads (8 waves =
// 2m x 4n). Halves the per-block weight L2->LDS staging (the r4 floor: 6.3 GB
// staged at BM=32) and halves barrier count at identical FLOPs.
//  - LDS = exactly 64KB: As 64x256 fp16 XOR-swizzled (chunk ^= row&7, no pad)
//    + Bs 2 x (256x32) fp16 ping-pong. 24-step pipelined loop, counted
//    vmcnt(2) (2 staging instrs per stage), prefetch chains across the
//    w2->wg->wf boundaries and the h2 epilogue (b2 preloaded to regs so the
//    epilogue issues no vm-ops -> no forced vmcnt(0) drain).
//  - ys is GONE: GLU output stays in registers; LN sums fused from regs via
//    shfl_xor over the 16 ln-lanes + red[64][4] cross-wave table aliased into
//    dead As. Kills r4's 8-way ys bank conflict and two full LDS passes.
//  - xs is GONE: elu x reads are wave-uniform -> s_loads; GLU reloads its 8.
//  - __expf for elu/sigmoid (fast v_exp path).
// ---------------------------------------------------------------------------
__global__ __launch_bounds__(512, 4) void grn_kernel(
    const float* __restrict__ x, const float* __restrict__ w1, const float* __restrict__ b1,
    const float* __restrict__ b2, const float* __restrict__ bg, const float* __restrict__ bfv_,
    const float* __restrict__ gamma, const float* __restrict__ beta,
    const float* __restrict__ wsk, const float* __restrict__ bsk,
    const _Float16* __restrict__ w2t, const _Float16* __restrict__ wgt,
    const _Float16* __restrict__ wft, _Float16* __restrict__ stacked, int tok_base)
{
    __shared__ __align__(16) char smem[65536];
    _Float16* As = (_Float16*)smem;                  // 64 x 256 fp16 swizzled (32KB)
    _Float16* Bs = (_Float16*)(smem + 32768);        // 2 x (256x32) fp16 (32KB)
    float* red = (float*)smem;                       // alias As (post-MFMA): 512 f32
    float* mv  = (float*)(smem + 2048);              // alias As: 128 f32

    const int f = blockIdx.y;
    const int tok0 = blockIdx.x * 64;                // chunk-local
    const int t = threadIdx.x;
    const int wv = t >> 6;
    const int ln = t & 15;
    const int q  = (t >> 4) & 3;
    const int wm = wv >> 2;                          // m-half 0/1
    const int wn = wv & 3;                           // n-quarter 0..3
    const int r0 = wm * 32 + ln;                     // A-frag row, mt=0
    const int r1 = r0 + 16;                          // A-frag row, mt=1

    const _Float16* w2f = w2t + (size_t)f * 65536;
    const _Float16* wgf = wgt + (size_t)f * 65536;
    const _Float16* wff = wft + (size_t)f * 65536;

#define GRN_STAGE(buf, Bsrc, kc) do {                                          \
        const _Float16* _bp = (Bsrc);                                          \
        _Pragma("unroll")                                                      \
        for (int _i = 0; _i < 2; ++_i) {                                       \
            int _s = t + _i * 512;                                             \
            int _row = _s >> 2;                                                \
            int _c = (_s & 3) ^ (_row & 3);                                    \
            GLD_LDS(_bp + _row * 256 + (kc) * 32 + _c * 8,                     \
                    Bs + (buf) * 8192 + _s * 8);                               \
        } } while (0)

#define GRN_MFMA(ACC, kc) do {                                                 \
        const _Float16* _B = Bs + ((kc) & 1) * 8192;                           \
        half8 _a0 = *(const half8*)&As[r0 * 256 + ((((kc) * 4 + q) ^ (r0 & 7)) << 3)]; \
        half8 _a1 = *(const half8*)&As[r1 * 256 + ((((kc) * 4 + q) ^ (r1 & 7)) << 3)]; \
        _Pragma("unroll")                                                      \
        for (int _nt = 0; _nt < 4; ++_nt) {                                    \
            int _rb = wn * 64 + _nt * 16 + ln;                                 \
            int _cp = q ^ (_rb & 3);                                           \
            half8 _b8 = *(const half8*)&_B[_rb * 32 + _cp * 8];                \
            ACC[0][_nt] = __builtin_amdgcn_mfma_f32_16x16x32_f16(              \
                _a0, _b8, ACC[0][_nt], 0, 0, 0);                               \
            ACC[1][_nt] = __builtin_amdgcn_mfma_f32_16x16x32_f16(              \
                _a1, _b8, ACC[1][_nt], 0, 0, 0);                               \
        } } while (0)

    // b2 preloaded (oldest in vm FIFO; retired by the first counted wait)
    float b2v[4];
#pragma unroll
    for (int nt = 0; nt < 4; ++nt) b2v[nt] = b2[f * H + wn * 64 + nt * 16 + ln];

    GRN_STAGE(0, w2f, 0);                            // first weight tile

    // A = elu(x * w1 + b1) -> As (swizzled). x reads are wave-uniform s_loads.
    {
        const int colE = t & 255;
        const int rgE = __builtin_amdgcn_readfirstlane(t >> 8) * 32;
        const float w1v = w1[f * H + colE];
        const float b1v = b1[f * H + colE];
        const int chE = colE >> 3, elE = colE & 7;
#pragma unroll 8
        for (int i = 0; i < 32; ++i) {
            int row = rgE + i;
            float xv = x[(size_t)(tok_base + tok0 + row) * F + f];
            float z = fmaf(xv, w1v, b1v);
            float e = z > 0.f ? z : (__expf(z) - 1.f);
            As[row * 256 + ((chE ^ (row & 7)) << 3) + elE] = (_Float16)e;
        }
    }
    LGKM_BAR();                                      // As visible; stage in flight

    float4v acc1[2][4];
#pragma unroll
    for (int mt = 0; mt < 2; ++mt)
#pragma unroll
        for (int nt = 0; nt < 4; ++nt)
#pragma unroll
            for (int r = 0; r < 4; ++r) acc1[mt][nt][r] = 0.f;

    // ---- stage 1: h2 = A @ w2 ----
#pragma unroll
    for (int kc = 0; kc < 8; ++kc) {
        if (kc < 7) GRN_STAGE((kc + 1) & 1, w2f, kc + 1);
        else        GRN_STAGE(0, wgf, 0);            // chain into stage 2
        WAITVM2_BAR();
        GRN_MFMA(acc1, kc);
        END_BAR();
    }

    // h2 + b2 -> As (swizzled fp16). No vm-ops here (b2 preloaded) so the
    // wg-kc0 prefetch stays in flight; lgkm-only barrier.
    {
#pragma unroll
        for (int mt = 0; mt < 2; ++mt)
#pragma unroll
            for (int nt = 0; nt < 4; ++nt) {
                int n = wn * 64 + nt * 16 + ln;
#pragma unroll
                for (int r = 0; r < 4; ++r) {
                    int row = wm * 32 + mt * 16 + q * 4 + r;
                    As[row * 256 + (((n >> 3) ^ (row & 7)) << 3) + (n & 7)] =
                        (_Float16)(acc1[mt][nt][r] + b2v[nt]);
                }
            }
    }
    LGKM_BAR();

    float4v accG[2][4], accF[2][4];
#pragma unroll
    for (int mt = 0; mt < 2; ++mt)
#pragma unroll
        for (int nt = 0; nt < 4; ++nt)
#pragma unroll
            for (int r = 0; r < 4; ++r) { accG[mt][nt][r] = 0.f; accF[mt][nt][r] = 0.f; }

    // ---- stage 2a: Cg = h2 @ wg ----
#pragma unroll
    for (int kc = 0; kc < 8; ++kc) {
        if (kc < 7) GRN_STAGE((kc + 1) & 1, wgf, kc + 1);
        else        GRN_STAGE(0, wff, 0);            // chain into wf
        WAITVM2_BAR();
        GRN_MFMA(accG, kc);
        END_BAR();
    }
    // ---- stage 2b: Cf = h2 @ wf ----
#pragma unroll
    for (int kc = 0; kc < 8; ++kc) {
        if (kc < 7) {
            GRN_STAGE((kc + 1) & 1, wff, kc + 1);
            WAITVM2_BAR();
        } else {
            WAITVM0_BAR();                           // final drain
        }
        GRN_MFMA(accF, kc);
        END_BAR();
    }
#undef GRN_STAGE
#undef GRN_MFMA

    // ---- GLU + residual, in registers (y overwrites accG) ----
    float xr[2][4];
#pragma unroll
    for (int mt = 0; mt < 2; ++mt)
#pragma unroll
        for (int r = 0; r < 4; ++r)
            xr[mt][r] = x[(size_t)(tok_base + tok0 + wm * 32 + mt * 16 + q * 4 + r) * F + f];
#pragma unroll
    for (int nt = 0; nt < 4; ++nt) {
        int nn = f * H + wn * 64 + nt * 16 + ln;
        float bgv = bg[nn], bfv = bfv_[nn], wsv = wsk[nn], bsv = bsk[nn];
#pragma unroll
        for (int mt = 0; mt < 2; ++mt)
#pragma unroll
            for (int r = 0; r < 4; ++r) {
                float cg = accG[mt][nt][r] + bgv;
                float cf = accF[mt][nt][r] + bfv;
                float sig = 1.f / (1.f + __expf(-cg));
                accG[mt][nt][r] = sig * cf + xr[mt][r] * wsv + bsv;
            }
    }

    // ---- LN sums fused from registers ----
    // per row: in-thread sum over 4 cols, shfl_xor over the 16 ln-lanes
    // (lane bits 0..3; q/row bits untouched), then red[row][wn] cross-wave.
#pragma unroll
    for (int mt = 0; mt < 2; ++mt)
#pragma unroll
        for (int r = 0; r < 4; ++r) {
            float v0 = accG[mt][0][r], v1 = accG[mt][1][r];
            float v2 = accG[mt][2][r], v3 = accG[mt][3][r];
            float s1 = (v0 + v1) + (v2 + v3);
            float s2 = (v0 * v0 + v1 * v1) + (v2 * v2 + v3 * v3);
#pragma unroll
            for (int m = 1; m <= 8; m <<= 1) {
                s1 += __shfl_xor(s1, m, 64);
                s2 += __shfl_xor(s2, m, 64);
            }
            if (ln == 0) {
                int row = wm * 32 + mt * 16 + q * 4 + r;
                red[row * 4 + wn] = s1;
                red[256 + row * 4 + wn] = s2;
            }
        }
    __syncthreads();
    if (t < 64) {
        float a = (red[t * 4] + red[t * 4 + 1]) + (red[t * 4 + 2] + red[t * 4 + 3]);
        float b = (red[256 + t * 4] + red[256 + t * 4 + 1])
                + (red[256 + t * 4 + 2] + red[256 + t * 4 + 3]);
        float mean = a * (1.f / 256.f);
        float var = b * (1.f / 256.f) - mean * mean;
        mv[t] = mean;
        mv[64 + t] = rsqrtf(var + 1e-5f);
    }
    __syncthreads();

    // ---- normalize + scale from registers, store fp16 ----
    float mr[2][4], rr[2][4];
#pragma unroll
    for (int mt = 0; mt < 2; ++mt)
#pragma unroll
        for (int r = 0; r < 4; ++r) {
            int row = wm * 32 + mt * 16 + q * 4 + r;
            mr[mt][r] = mv[row];
            rr[mt][r] = mv[64 + row];
        }
#pragma unroll
    for (int nt = 0; nt < 4; ++nt) {
        int n = wn * 64 + nt * 16 + ln;
        float gv = gamma[f * H + n], bvv = beta[f * H + n];
#pragma unroll
        for (int mt = 0; mt < 2; ++mt)
#pragma unroll
            for (int r = 0; r < 4; ++r) {
                int row = wm * 32 + mt * 16 + q * 4 + r;
                float vv = (accG[mt][nt][r] - mr[mt][r]) * rr[mt][r] * gv + bvv;
                stacked[(size_t)(tok0 + row) * FH + f * H + n] = (_Float16)vv;
            }
    }
}

// ---------------------------------------------------------------------------
// Selection GEMM v3: BM=64, BK=64, 256 threads (4 waves, one n-column each).
// A (stacked) double-buffered in LDS via global_load_lds with XOR swizzle.
// B (wcat, L2-resident) loaded straight to registers each K-step. All
// accumulator indexing compile-time static (rule #20).
// ---------------------------------------------------------------------------
__global__ __launch_bounds__(256, 3) void sel_gemm_kernel(
    const _Float16* __restrict__ stacked, const _Float16* __restrict__ wcat,
    float* __restrict__ sh_part, float* __restrict__ sres_part, int C)
{
    __shared__ __align__(16) _Float16 As2[2][64 * 64];   // 2 x 8 KB
    const int t = threadIdx.x;
    const int wv = t >> 6;
    const int ln = t & 15, q = (t & 63) >> 4;
    const int tok0 = blockIdx.x * 64;                    // chunk-local
    const int kb = blockIdx.y;                           // k-slice 0..3

    const int s1 = t + 256;
    const int row0 = t >> 3,  c0 = ((t & 7) ^ (row0 & 7)) * 8;
    const int row1 = s1 >> 3, c1 = ((s1 & 7) ^ (row1 & 7)) * 8;
    const _Float16* a0src = stacked + (size_t)(tok0 + row0) * FH + kb * 2048 + c0;
    const _Float16* a1src = stacked + (size_t)(tok0 + row1) * FH + kb * 2048 + c1;

    float4v acc[4][5];
#pragma unroll
    for (int mt = 0; mt < 4; ++mt)
#pragma unroll
        for (int i = 0; i < 5; ++i)
#pragma unroll
            for (int r = 0; r < 4; ++r) acc[mt][i][r] = 0.f;

    GLD_LDS(a0src, &As2[0][t * 8]);
    GLD_LDS(a1src, &As2[0][s1 * 8]);
    __syncthreads();

    for (int kc = 0; kc < 32; ++kc) {
        const int cur = kc & 1;
        // ---- B fragments for this K-step: global->reg, issued FIRST ----
        half8 bb0[5], bb1[5];
#define SEL_LOAD(i)                                                            \
        {                                                                      \
            const _Float16* bp = wcat                                          \
                + (size_t)((wv + 4 * (i)) * 16 + ln) * FH                      \
                + kb * 2048 + kc * 64 + q * 8;                                 \
            bb0[i] = *(const half8*)bp;                                        \
            bb1[i] = *(const half8*)(bp + 32);                                 \
        }
        SEL_LOAD(0) SEL_LOAD(1) SEL_LOAD(2) SEL_LOAD(3)
        if (wv < 2) SEL_LOAD(4)
#undef SEL_LOAD
        // ---- prefetch next A tile into the other buffer ----
        if (kc < 31) {
            GLD_LDS(a0src + (kc + 1) * 64, &As2[cur ^ 1][t * 8]);
            GLD_LDS(a1src + (kc + 1) * 64, &As2[cur ^ 1][s1 * 8]);
        }
        // ---- A fragments from LDS (swizzled, conflict-free) ----
        const _Float16* As = As2[cur];
        half8 af0[4], af1[4];
#pragma unroll
        for (int mt = 0; mt < 4; ++mt) {
            int row = mt * 16 + ln;
            af0[mt] = *(const half8*)&As[row * 64 + ((q ^ (row & 7)) * 8)];
            af1[mt] = *(const half8*)&As[row * 64 + (((4 + q) ^ (row & 7)) * 8)];
        }
        // ---- MFMA, fully static indexing ----
#define SEL_FMA(i)                                                             \
        {                                                                      \
            _Pragma("unroll")                                                  \
            for (int mt = 0; mt < 4; ++mt)                                     \
                acc[mt][i] = __builtin_amdgcn_mfma_f32_16x16x32_f16(           \
                    af0[mt], bb0[i], acc[mt][i], 0, 0, 0);                     \
            _Pragma("unroll")                                                  \
            for (int mt = 0; mt < 4; ++mt)                                     \
                acc[mt][i] = __builtin_amdgcn_mfma_f32_16x16x32_f16(           \
                    af1[mt], bb1[i], acc[mt][i], 0, 0, 0);                     \
        }
        SEL_FMA(0) SEL_FMA(1) SEL_FMA(2) SEL_FMA(3)
        if (wv < 2) SEL_FMA(4)
#undef SEL_FMA
        __syncthreads();   // drains prefetch; all waves done reading buf[cur]
    }

    // ---- epilogue: plain stores, static branches ----
    float* shp = sh_part + (size_t)kb * ((size_t)C * 256);
    float* srp = sres_part + (size_t)kb * ((size_t)C * 32);
#pragma unroll
    for (int i = 0; i < 4; ++i) {
        int n = (wv + 4 * i) * 16 + ln;                  // always < 256
#pragma unroll
        for (int mt = 0; mt < 4; ++mt)
#pragma unroll
            for (int r = 0; r < 4; ++r) {
                int m = tok0 + mt * 16 + q * 4 + r;
                shp[(size_t)m * 256 + n] = acc[mt][i][r];
            }
    }
    if (wv < 2) {                                        // tile 4 = sres cols
        int n = wv * 16 + ln;                            // 0..31
#pragma unroll
        for (int mt = 0; mt < 4; ++mt)
#pragma unroll
            for (int r = 0; r < 4; ++r) {
                int m = tok0 + mt * 16 + q * 4 + r;
                srp[(size_t)m * 32 + n] = acc[mt][4][r];
            }
    }
}

// ---------------------------------------------------------------------------
// Fused selection tail + weighted sum. Block = 8 tokens (32 lanes each).
// Reduces the 4 split-K partials (+bias) -> elu -> fc2(256->32) -> GLU -> LN
// -> softmax -> out = sum_f stacked*w
// ---------------------------------------------------------------------------
__global__ __launch_bounds__(256) void tail_kernel(
    const float* __restrict__ sh_part, const float* __restrict__ sres_part,
    const _Float16* __restrict__ stacked,
    const float* __restrict__ sb1, const float* __restrict__ ssb,
    const float* __restrict__ sw2, const float* __restrict__ sb2,
    const float* __restrict__ swg, const float* __restrict__ sbg,
    const float* __restrict__ swf, const float* __restrict__ sbf,
    const float* __restrict__ sgam, const float* __restrict__ sbet,
    float* __restrict__ out, int tok_base, int C)
{
    __shared__ float sw2s[256 * 32];                    // 32 KB
    __shared__ float swgs[1024], swfs[1024];            // 8 KB
    __shared__ float shv[8][257];                       // 8 tokens x 256 (+pad)
    __shared__ float wls[8][33];
    const int t = threadIdx.x;
    const size_t shS = (size_t)C * 256;
    const size_t srS = (size_t)C * 32;
    for (int i = 0; i < 32; ++i) sw2s[t + i * 256] = sw2[t + i * 256];
    for (int i = 0; i < 4; ++i) {
        swgs[t + i * 256] = swg[t + i * 256];
        swfs[t + i * 256] = swf[t + i * 256];
    }
    // reduce split-K partials + bias, elu, stage for 8 tokens
    for (int i = 0; i < 8; ++i) {
        int idx = t + i * 256;
        int gg = idx >> 8, col = idx & 255;
        size_t o = (size_t)(blockIdx.x * 8 + gg) * 256 + col;
        float z = sb1[col] + sh_part[o] + sh_part[shS + o]
                + sh_part[2 * shS + o] + sh_part[3 * shS + o];
        shv[gg][col] = z > 0.f ? z : (__expf(z) - 1.f);
    }
    __syncthreads();
    const int g = t >> 5;                               // token group 0..7
    const int j = t & 31;                               // feature index
    const int token = blockIdx.x * 8 + g;               // chunk-local
    // fc2: 256 -> 32
    float p = sb2[j];
    for (int k = 0; k < 256; ++k) p += shv[g][k] * sw2s[k * 32 + j];
    // GLU via width-32 shuffles
    float gacc = sbg[j], uacc = sbf[j];
#pragma unroll 8
    for (int i = 0; i < 32; ++i) {
        float tv = __shfl(p, i, 32);
        gacc += tv * swgs[i * 32 + j];
        uacc += tv * swfs[i * 32 + j];
    }
    float sig = 1.f / (1.f + __expf(-gacc));
    size_t o2 = (size_t)token * 32 + j;
    float sresv = ssb[j] + sres_part[o2] + sres_part[srS + o2]
                + sres_part[2 * srS + o2] + sres_part[3 * srS + o2];
    float sv = sresv + sig * uacc;
    // LayerNorm over 32 lanes
    float s1 = sv, s2 = sv * sv;
    for (int off = 16; off; off >>= 1) {
        s1 += __shfl_xor(s1, off, 32);
        s2 += __shfl_xor(s2, off, 32);
    }
    float mean = s1 * (1.f / 32.f);
    float var = s2 * (1.f / 32.f) - mean * mean;
    float v = (sv - mean) * rsqrtf(var + 1e-5f) * sgam[j] + sbet[j];
    // softmax over 32 lanes
    float mx = v;
    for (int off = 16; off; off >>= 1) mx = fmaxf(mx, __shfl_xor(mx, off, 32));
    float e = __expf(v - mx);
    float ssum = e;
    for (int off = 16; off; off >>= 1) ssum += __shfl_xor(ssum, off, 32);
    wls[g][j] = e / ssum;
    __syncthreads();
    // weighted sum over features for the block's 8 tokens
    for (int tk = 0; tk < 8; ++tk) {
        const _Float16* sp = stacked + (size_t)(blockIdx.x * 8 + tk) * FH;
        float a = 0.f;
#pragma unroll
        for (int f = 0; f < 32; ++f) a += (float)sp[f * 256 + t] * wls[tk][f];
        out[(size_t)(tok_base + blockIdx.x * 8 + tk) * 256 + t] = a;
    }
}

// ---------------------------------------------------------------------------
extern "C" void kernel_launch(void* const* d_in, const int* in_sizes, int n_in,
                              void* d_out, int out_size, void* d_ws, size_t ws_size,
                              hipStream_t stream)
{
    (void)in_sizes; (void)n_in; (void)out_size;
    const float* x    = (const float*)d_in[0];
    const float* w1   = (const float*)d_in[1];
    const float* b1   = (const float*)d_in[2];
    const float* w2   = (const float*)d_in[3];
    const float* b2   = (const float*)d_in[4];
    const float* wg   = (const float*)d_in[5];
    const float* bg   = (const float*)d_in[6];
    const float* wf   = (const float*)d_in[7];
    const float* bfp  = (const float*)d_in[8];
    const float* gamma= (const float*)d_in[9];
    const float* beta = (const float*)d_in[10];
    const float* wsk  = (const float*)d_in[11];
    const float* bsk  = (const float*)d_in[12];
    const float* sw1  = (const float*)d_in[13];
    const float* sb1  = (const float*)d_in[14];
    const float* sw2  = (const float*)d_in[15];
    const float* sb2  = (const float*)d_in[16];
    const float* swg  = (const float*)d_in[17];
    const float* sbg  = (const float*)d_in[18];
    const float* swf  = (const float*)d_in[19];
    const float* sbf  = (const float*)d_in[20];
    const float* sgam = (const float*)d_in[21];
    const float* sbet = (const float*)d_in[22];
    const float* ssw  = (const float*)d_in[23];
    const float* ssb  = (const float*)d_in[24];

    // ---- workspace layout, chunk size adaptive to ws_size ----
    // per-token: stacked 16384B + sh_part 4*1024B + sres_part 4*128B = 20992B
    const size_t fixedB = 12582912 + 4718592;            // wt (12 MiB) + wcat (4.5 MiB)
    int C = BT;                                          // tokens per chunk
    while (C > 512) {
        size_t need = fixedB + (size_t)C * 20992;
        if (need <= ws_size) break;
        C >>= 1;
    }
    const int nChunks = BT / C;

    char* ws = (char*)d_ws;
    _Float16* wt      = (_Float16*)ws;                                   // 3 x 2M fp16
    _Float16* wcat    = (_Float16*)(ws + 12582912);                      // 288 x 8192 fp16
    char* p = ws + fixedB;
    _Float16* stacked = (_Float16*)p;            p += (size_t)C * FH * 2;
    float* sh_part    = (float*)p;               p += (size_t)C * 256 * 4 * SPLITK;
    float* sres_part  = (float*)p;
    float* out        = (float*)d_out;

    hipLaunchKernelGGL(transpose_w_kernel, dim3(1536), dim3(256), 0, stream, w2, wg, wf, wt);
    hipLaunchKernelGGL(transpose_s_kernel, dim3(640), dim3(256), 0, stream, sw1, ssw, wcat);
    for (int c = 0; c < nChunks; ++c) {
        int tb = c * C;
        hipLaunchKernelGGL(grn_kernel, dim3(C / 64, 32), dim3(512), 0, stream,
                           x, w1, b1, b2, bg, bfp, gamma, beta, wsk, bsk,
                           wt, wt + 2097152, wt + 2 * 2097152, stacked, tb);
        hipLaunchKernelGGL(sel_gemm_kernel, dim3(C / 64, SPLITK), dim3(256), 0, stream,
                           stacked, wcat, sh_part, sres_part, C);
        hipLaunchKernelGGL(tail_kernel, dim3(C / 8), dim3(256), 0, stream,
                           sh_part, sres_part, stacked, sb1, ssb, sw2, sb2, swg, sbg, swf, sbf,
                           sgam, sbet, out, tb, C);
    }
}